// Round 9
// baseline (780.974 us; speedup 1.0000x reference)
//
#include <hip/hip_runtime.h>

#define S_LEN  1024
#define H_DIM  4096
#define NHEAD  32
#define HEAD_D 128
#define RANK   16
#define KE3    4160   // QKV extended K: 4096 + 3*16 + 16 pad (130 * 32)
#define KEO    4160   // O-proj extended K: 4096 + 16 + 48 pad (65 * 64) — 64-mult for BK=64
#define TOTP   ((long)NHEAD * S_LEN * S_LEN)

typedef __bf16 bf16x8 __attribute__((ext_vector_type(8)));
typedef float  f32x4  __attribute__((ext_vector_type(4)));
typedef unsigned short ushort8v __attribute__((ext_vector_type(8)));

#define GLOAD_LDS16(g, l) __builtin_amdgcn_global_load_lds( \
    (const __attribute__((address_space(1))) unsigned int*)(g), \
    (__attribute__((address_space(3))) unsigned int*)(l), 16, 0, 0)

__device__ const float NF4_TAB[16] = {
    -1.0f, -0.6961928009986877f, -0.5250730514526367f, -0.39491748809814453f,
    -0.28444138169288635f, -0.18477343022823334f, -0.09105003625154495f, 0.0f,
    0.07958029955625534f, 0.16093020141124725f, 0.24611230194568634f,
    0.33791524171829224f, 0.4407098591327667f, 0.5626170039176941f,
    0.7229568362236023f, 1.0f};

__device__ __forceinline__ unsigned short f2bf(float f) {
    unsigned int u = __builtin_bit_cast(unsigned int, f);
    u = (u + 0x7FFFu + ((u >> 16) & 1u)) >> 16;   // RNE
    return (unsigned short)u;
}

__device__ __forceinline__ float bf2f(unsigned short s) {
    return __builtin_bit_cast(float, (unsigned int)s << 16);
}

// ---------------- plain dequant NF4 -> bf16, strided output row ----------------
__device__ __forceinline__ void dequant_body(
    const int* __restrict__ codes, const float* __restrict__ absmax,
    unsigned short* __restrict__ out, long i, int ostride) {
    int4 c0 = *(const int4*)(codes + i);
    int4 c1 = *(const int4*)(codes + i + 4);
    float am = absmax[i >> 6];
    long orow = i >> 12;                 // H_DIM = 4096
    int  col  = (int)(i & 4095);
    ushort8v r;
    r[0] = f2bf(NF4_TAB[c0.x] * am);
    r[1] = f2bf(NF4_TAB[c0.y] * am);
    r[2] = f2bf(NF4_TAB[c0.z] * am);
    r[3] = f2bf(NF4_TAB[c0.w] * am);
    r[4] = f2bf(NF4_TAB[c1.x] * am);
    r[5] = f2bf(NF4_TAB[c1.y] * am);
    r[6] = f2bf(NF4_TAB[c1.z] * am);
    r[7] = f2bf(NF4_TAB[c1.w] * am);
    *(ushort8v*)(out + orow * ostride + col) = r;
}

// -------- x cast + 3x lora_a, one row per block ----
__global__ __launch_bounds__(256) void xcast_lora(
    const float* __restrict__ x, const float* __restrict__ la0,
    const float* __restrict__ la1, const float* __restrict__ la2,
    unsigned short* __restrict__ xb_ext) {
    __shared__ float xs[4096];
    int m = (int)blockIdx.x;
    int tid = threadIdx.x;
    const float* xr = x + (long)m * H_DIM;
    int c = tid * 16;
    float4 f0 = *(const float4*)(xr + c);
    float4 f1 = *(const float4*)(xr + c + 4);
    float4 f2 = *(const float4*)(xr + c + 8);
    float4 f3 = *(const float4*)(xr + c + 12);
    *(float4*)(xs + c)      = f0;
    *(float4*)(xs + c + 4)  = f1;
    *(float4*)(xs + c + 8)  = f2;
    *(float4*)(xs + c + 12) = f3;
    ushort8v r0, r1;
    r0[0] = f2bf(f0.x); r0[1] = f2bf(f0.y); r0[2] = f2bf(f0.z); r0[3] = f2bf(f0.w);
    r0[4] = f2bf(f1.x); r0[5] = f2bf(f1.y); r0[6] = f2bf(f1.z); r0[7] = f2bf(f1.w);
    r1[0] = f2bf(f2.x); r1[1] = f2bf(f2.y); r1[2] = f2bf(f2.z); r1[3] = f2bf(f2.w);
    r1[4] = f2bf(f3.x); r1[5] = f2bf(f3.y); r1[6] = f2bf(f3.z); r1[7] = f2bf(f3.w);
    unsigned short* orow = xb_ext + (long)m * KE3 + c;
    *(ushort8v*)orow = r0;
    *(ushort8v*)(orow + 8) = r1;
    __syncthreads();
    int w = tid >> 6, lane = tid & 63;
    if (w < 3) {
        const float* la = (w == 0) ? la0 : (w == 1) ? la1 : la2;
        float s[16];
#pragma unroll
        for (int r = 0; r < 16; ++r) s[r] = 0.f;
        for (int k = lane; k < H_DIM; k += 64) {
            float xv = xs[k];
            const float4* lr = (const float4*)(la + (long)k * RANK);
            float4 q0 = lr[0], q1 = lr[1], q2 = lr[2], q3 = lr[3];
            s[0] += xv * q0.x;  s[1] += xv * q0.y;  s[2] += xv * q0.z;  s[3] += xv * q0.w;
            s[4] += xv * q1.x;  s[5] += xv * q1.y;  s[6] += xv * q1.z;  s[7] += xv * q1.w;
            s[8] += xv * q2.x;  s[9] += xv * q2.y;  s[10] += xv * q2.z; s[11] += xv * q2.w;
            s[12] += xv * q3.x; s[13] += xv * q3.y; s[14] += xv * q3.z; s[15] += xv * q3.w;
        }
        for (int off = 32; off; off >>= 1)
#pragma unroll
            for (int r = 0; r < 16; ++r) s[r] += __shfl_xor(s[r], off);
        if (lane == 0)
#pragma unroll
            for (int r = 0; r < 16; ++r)
                xb_ext[(long)m * KE3 + 4096 + 16 * w + r] = f2bf(s[r]);
    } else if (lane < 16) {
        // zero the 16 alignment-pad columns [4144,4160)
        xb_ext[(long)m * KE3 + 4144 + lane] = 0;
    }
}

// -------- prep: 4 dequants + lbT pads + bias + hist zero (no LDS) --------
// grid dim3(9600, 4):
//  bx<8192               : dequant main region (all p), one-shot 8 elem/thread
//  p<3,  bx in [8192,9216): lbT/zero pad cols (64/row) + bias gather
//  p==3, bx in [8192,9216): wo pad cols (64/row, KEO=4160)
//  p==1, bx in [9216,9600): zero hist buffer (6*16384 uints)
// NOTE (round 8 lesson): moving the Wd dequant into the QKV GEMM as 192
// grid-stride blocks REGRESSED +65us — a fused BW-region needs the same
// TLP shape as the standalone kernel (2048 one-shot blocks), not a few
// long-running stride loops.
__global__ __launch_bounds__(256) void prep_weights(
    const int* __restrict__ c0, const int* __restrict__ c1,
    const int* __restrict__ c2, const int* __restrict__ c3,
    const float* __restrict__ a0, const float* __restrict__ a1,
    const float* __restrict__ a2, const float* __restrict__ a3,
    const float* __restrict__ lb0, const float* __restrict__ lb1,
    const float* __restrict__ lb2, const float* __restrict__ lb3,
    const float* __restrict__ b0, const float* __restrict__ b1,
    const float* __restrict__ b2,
    unsigned short* __restrict__ wqkv, unsigned short* __restrict__ wo,
    float* __restrict__ bias3, unsigned int* __restrict__ hist, long n) {
    int p = blockIdx.y;
    long bx = blockIdx.x;
    int tid = threadIdx.x;
    if (bx < 8192) {
        const int* codes = (p == 0) ? c0 : (p == 1) ? c1 : (p == 2) ? c2 : c3;
        const float* am  = (p == 0) ? a0 : (p == 1) ? a1 : (p == 2) ? a2 : a3;
        long i = (bx * 256 + tid) * 8;
        if (i >= n) return;
        if (p < 3) dequant_body(codes, am, wqkv + (size_t)p * H_DIM * KE3, i, KE3);
        else       dequant_body(codes, am, wo, i, KEO);
        return;
    }
    if (bx < 9216) {
        long g = (bx - 8192) * 256 + tid;
        int row = (int)(g >> 6), c = (int)(g & 63);
        if (p < 3) {
            const float* lb = (p == 0) ? lb0 : (p == 1) ? lb1 : lb2;
            unsigned int r = (unsigned int)(c - 16 * p);
            float v = (r < 16u) ? lb[r * H_DIM + row] : 0.f;
            wqkv[(size_t)p * H_DIM * KE3 + (long)row * KE3 + 4096 + c] = f2bf(v);
            if (g < H_DIM) {
                const float* bp = (p == 0) ? b0 : (p == 1) ? b1 : b2;
                bias3[(size_t)p * H_DIM + g] = bp[g];
            }
            return;
        }
        // p == 3: wo pad cols [4096,4160)
        float v = (c < 16) ? lb3[c * H_DIM + row] : 0.f;
        wo[(long)row * KEO + 4096 + c] = f2bf(v);
        return;
    }
    if (p == 1) {
        long g = (bx - 9216) * 256 + tid;
        if (g < 6 * 16384) hist[g] = 0u;
    }
}

// xa_o = ob @ la_o (bf16 in) -> bf16 cols of ob_ext — ushort8-vectorized x loads
__global__ __launch_bounds__(256) void lora_ao_kernel(
    unsigned short* __restrict__ ob_ext, const float* __restrict__ la) {
    int m = blockIdx.x;
    const unsigned short* xr = ob_ext + (long)m * KEO;
    int tid = threadIdx.x, lane = tid & 63, wid = tid >> 6;
    float s[4] = {0.f, 0.f, 0.f, 0.f};
    for (int k0 = lane * 8; k0 < H_DIM; k0 += 512) {     // 8 iters, 16B/lane
        ushort8v xv8 = *(const ushort8v*)(xr + k0);
#pragma unroll
        for (int j = 0; j < 8; ++j) {
            float xv = bf2f(xv8[j]);
            float4 q = *(const float4*)(la + (long)(k0 + j) * RANK + wid * 4);
            s[0] += xv * q.x; s[1] += xv * q.y;
            s[2] += xv * q.z; s[3] += xv * q.w;
        }
    }
    for (int off = 32; off; off >>= 1)
        for (int r = 0; r < 4; ++r) s[r] += __shfl_down(s[r], off);
    if (lane == 0) {
        for (int r = 0; r < 4; ++r)
            ob_ext[(long)m * KEO + 4096 + wid * 4 + r] = f2bf(s[r]);
        // zero pad cols [4112,4160): 12 per wave
        for (int r = 0; r < 12; ++r)
            ob_ext[(long)m * KEO + 4112 + wid * 12 + r] = 0;
    }
}

// ---------------- bf16 NT GEMM body: C[m][n] = alpha*sum_k A[m][k]*B[n][k] (+bias[n]) --
// BK=64, 128B LDS rows, XOR slot-swizzle (slot ^= row&7) -> conflict-free ds_read_b128.
// Single-buffer 2-barrier structure (measured 848 TF, 0 conflicts — round 5).
// NOTE (round 6 lesson): explicit dbuf + 64KB LDS REGRESSED to 593 TF (occupancy
// 30->16.5%, FETCH +40%) — reproduces learn_hip m132. Do not re-attempt at 128² tile.
// MODE 0: plain batched (z). MODE 1: causal triangular grid (x<36: tri idx, z=head;
//         x in [36,40): v->vT transpose region). MODE 2: batched + K limited to
//         bm+128 (causal PV). MODE 3: split-K2 (z half -> Cv/Cv2, f32 out).
template<int MODE>
__device__ __forceinline__ void gemm_body(
    const unsigned short* __restrict__ A, const unsigned short* __restrict__ B,
    void* __restrict__ Cv, void* __restrict__ Cv2, const float* __restrict__ bias,
    int K, int lda, int ldb, int ldc,
    long strideA, long strideB, long strideC, float alpha,
    const unsigned short* __restrict__ tsrc, unsigned short* __restrict__ tdst) {
    __shared__ unsigned short As[128][64];   // 16 KB each, 128B rows (8 swizzle slots)
    __shared__ unsigned short Bs[128][64];
    const int tid = threadIdx.x;
    int bm, bn;
    int k0s = 0, k0e = K;
    if (MODE == 1) {
        int i = blockIdx.x;
        if (i >= 36) {
            // transpose region: 128 blocks, 32x32 tiles, padded LDS overlay
            unsigned short (*tl)[33] = (unsigned short(*)[33])&As[0][0];
            int tb = (i - 36) + 4 * blockIdx.z;
            int tx = tid & 31, ty = tid >> 5;           // 8 rows per pass
            for (int tile = tb; tile < 4096; tile += 128) {
                int tc = tile & 127, ts = tile >> 7;
                int c0 = tc * 32, s0 = ts * 32;
                for (int j = 0; j < 32; j += 8)
                    tl[ty + j][tx] = tsrc[(long)(s0 + ty + j) * H_DIM + c0 + tx];
                __syncthreads();
                for (int j = 0; j < 32; j += 8)
                    tdst[(long)(c0 + ty + j) * S_LEN + s0 + tx] = tl[tx][ty + j];
                __syncthreads();
            }
            return;
        }
        int tm = (int)((sqrtf(8.f * i + 1.f) - 1.f) * 0.5f);
        if ((tm + 1) * (tm + 2) / 2 <= i) tm++;
        if (tm * (tm + 1) / 2 > i) tm--;
        int tn = i - tm * (tm + 1) / 2;
        bm = tm * 128; bn = tn * 128;
    } else {
        bm = blockIdx.y * 128; bn = blockIdx.x * 128;
        if (MODE == 2) { int kl = bm + 128; if (kl < k0e) k0e = kl; }
    }
    const unsigned short* Ab = A;
    const unsigned short* Bb = B;
    long coff = 0;
    void* Cuse = Cv;
    if (MODE == 3) {
        int Kh = (K / 2) & ~63;
        k0s = blockIdx.z ? Kh : 0;
        k0e = blockIdx.z ? K : Kh;
        Cuse = blockIdx.z ? Cv2 : Cv;
    } else {
        Ab += (long)blockIdx.z * strideA;
        Bb += (long)blockIdx.z * strideB;
        coff = (long)blockIdx.z * strideC;
    }
    const int lane = tid & 63, wid = tid >> 6;
    const int wm = (wid >> 1) * 64, wn = (wid & 1) * 64;
    // staging: pass p covers LDS rows [p*32 + wid*8, +8); lane -> row l>>3, slot l&7
    const int srow = lane >> 3;
    const int scol = ((lane & 7) ^ srow) << 3;          // pre-swizzled source col
    const int r0 = wid * 8 + srow;
    const unsigned short* gA0 = Ab + (long)(bm + r0) * lda + scol;
    const unsigned short* gB0 = Bb + (long)(bn + r0) * ldb + scol;
    f32x4 acc[4][4] = {};
    const int q = lane >> 4, rr = lane & 15;
    const int colh0 = ((q ^ (rr & 7)) << 3);            // k-half 0 slots (0..3 ^ row)
    const int colh1 = colh0 ^ 32;                       // k-half 1 (bit2 of slot)
    for (int k0 = k0s; k0 < k0e; k0 += 64) {
#pragma unroll
        for (int p = 0; p < 4; ++p) {
            GLOAD_LDS16(gA0 + (long)p * 32 * lda + k0, &As[p * 32 + wid * 8][0]);
            GLOAD_LDS16(gB0 + (long)p * 32 * ldb + k0, &Bs[p * 32 + wid * 8][0]);
        }
        __syncthreads();
        bf16x8 af[4], bfr[4];
#pragma unroll
        for (int i = 0; i < 4; ++i) {
            af[i]  = __builtin_bit_cast(bf16x8, *(const uint4*)&As[wm + i * 16 + rr][colh0]);
            bfr[i] = __builtin_bit_cast(bf16x8, *(const uint4*)&Bs[wn + i * 16 + rr][colh0]);
        }
#pragma unroll
        for (int i = 0; i < 4; ++i)
#pragma unroll
            for (int j = 0; j < 4; ++j)
                acc[i][j] = __builtin_amdgcn_mfma_f32_16x16x32_bf16(
                    af[i], bfr[j], acc[i][j], 0, 0, 0);
#pragma unroll
        for (int i = 0; i < 4; ++i) {
            af[i]  = __builtin_bit_cast(bf16x8, *(const uint4*)&As[wm + i * 16 + rr][colh1]);
            bfr[i] = __builtin_bit_cast(bf16x8, *(const uint4*)&Bs[wn + i * 16 + rr][colh1]);
        }
#pragma unroll
        for (int i = 0; i < 4; ++i)
#pragma unroll
            for (int j = 0; j < 4; ++j)
                acc[i][j] = __builtin_amdgcn_mfma_f32_16x16x32_bf16(
                    af[i], bfr[j], acc[i][j], 0, 0, 0);
        __syncthreads();
    }
    const int cr = (lane >> 4) * 4;
    const int cc = lane & 15;
    float bv[4];
#pragma unroll
    for (int j = 0; j < 4; ++j)
        bv[j] = bias ? bias[(long)blockIdx.z * H_DIM + bn + wn + j * 16 + cc] : 0.f;
    if (MODE != 3) {
        unsigned short* Cb = (unsigned short*)Cuse + coff;
        for (int i = 0; i < 4; ++i)
            for (int j = 0; j < 4; ++j) {
                unsigned short* cp = Cb + (long)(bm + wm + i * 16 + cr) * ldc
                                        + (bn + wn + j * 16 + cc);
                for (int r = 0; r < 4; ++r)
                    cp[(long)r * ldc] = f2bf(acc[i][j][r] * alpha + bv[j]);
            }
    } else {
        float* Cb = (float*)Cuse + coff;
        for (int i = 0; i < 4; ++i)
            for (int j = 0; j < 4; ++j) {
                float* cp = Cb + (long)(bm + wm + i * 16 + cr) * ldc
                               + (bn + wn + j * 16 + cc);
                for (int r = 0; r < 4; ++r)
                    cp[(long)r * ldc] = acc[i][j][r] * alpha + bv[j];
            }
    }
}

// Named wrappers — distinct Kernel_Name per GEMM stage for rocprof attribution.
__global__ __launch_bounds__(256) void gemm_qkv(
    const unsigned short* __restrict__ A, const unsigned short* __restrict__ B,
    void* __restrict__ Cv, const float* __restrict__ bias) {
    gemm_body<0>(A, B, Cv, nullptr, bias, KE3, KE3, KE3, H_DIM,
                 0, (long)H_DIM * KE3, (long)S_LEN * H_DIM, 1.0f, nullptr, nullptr);
}

__global__ __launch_bounds__(256) void gemm_scores(
    const unsigned short* __restrict__ A, const unsigned short* __restrict__ B,
    void* __restrict__ Cv, const unsigned short* __restrict__ tsrc,
    unsigned short* __restrict__ tdst) {
    gemm_body<1>(A, B, Cv, nullptr, nullptr, HEAD_D, H_DIM, H_DIM, S_LEN,
                 128, 128, (long)S_LEN * S_LEN, 0.08838834764831845f, tsrc, tdst);
}

__global__ __launch_bounds__(256) void gemm_pv(
    const unsigned short* __restrict__ A, const unsigned short* __restrict__ B,
    void* __restrict__ Cv) {
    gemm_body<2>(A, B, Cv, nullptr, nullptr, S_LEN, S_LEN, S_LEN, KEO,
                 (long)S_LEN * S_LEN, (long)HEAD_D * S_LEN, 128, 1.0f,
                 nullptr, nullptr);
}

__global__ __launch_bounds__(256) void gemm_oproj(
    const unsigned short* __restrict__ A, const unsigned short* __restrict__ B,
    void* __restrict__ Cv, void* __restrict__ Cv2) {
    gemm_body<3>(A, B, Cv, Cv2, nullptr, KEO, KEO, KEO, H_DIM,
                 0, 0, 0, 1.0f, nullptr, nullptr);
}

// ---------------- causal softmax, bf16 in/out in-place, 2 balanced rows/block ----
__global__ __launch_bounds__(256) void softmax_causal(unsigned short* __restrict__ scores16) {
    int b = blockIdx.x;
    int h = b >> 9, pr = b & 511;
    int tid = threadIdx.x, lane = tid & 63, wid = tid >> 6;
    __shared__ float red[4], red2[4];
    for (int half = 0; half < 2; ++half) {
        int i = half ? (S_LEN - 1 - pr) : pr;
        unsigned short* row = scores16 + ((long)h * S_LEN + i) * S_LEN;
        int L = i + 1;
        float v[4];
        float mx = -1e30f;
        for (int t = 0; t < 4; ++t) {
            int j = tid + (t << 8);
            v[t] = (j < L) ? bf2f(row[j]) : -1e30f;
            mx = fmaxf(mx, v[t]);
        }
        for (int off = 32; off; off >>= 1) mx = fmaxf(mx, __shfl_xor(mx, off));
        if (lane == 0) red[wid] = mx;
        __syncthreads();
        mx = fmaxf(fmaxf(red[0], red[1]), fmaxf(red[2], red[3]));
        float e[4], sum = 0.f;
        for (int t = 0; t < 4; ++t) {
            int j = tid + (t << 8);
            e[t] = (j < L) ? __expf(v[t] - mx) : 0.f;
            sum += e[t];
        }
        for (int off = 32; off; off >>= 1) sum += __shfl_xor(sum, off);
        if (lane == 0) red2[wid] = sum;
        __syncthreads();
        sum = red2[0] + red2[1] + red2[2] + red2[3];
        float inv = 1.f / sum;
        for (int t = 0; t < 4; ++t) {
            int j = tid + (t << 8);
            row[j] = f2bf(e[t] * inv);
        }
        __syncthreads();
    }
}

// ---------------- mega histogram: 6 tensors, flat weighted grid (1536 blocks) ----
// [0,256) x fp32 | [256,384) q | [384,512) k | [512,640) v | [640,768) o | [768,1536) P
__global__ __launch_bounds__(256, 2) void hist6(
    const float* __restrict__ x, const unsigned short* __restrict__ qkv,
    const unsigned short* __restrict__ ob, const unsigned short* __restrict__ P,
    unsigned int* __restrict__ hist) {
    __shared__ unsigned int lh[16384];
    const long SH = (long)S_LEN * H_DIM;
    int t = threadIdx.x;
    int b = blockIdx.x;
    int ten, b0, nblk;
    if (b < 256)      { ten = 0; b0 = 0;   nblk = 256; }
    else if (b < 384) { ten = 1; b0 = 256; nblk = 128; }
    else if (b < 512) { ten = 2; b0 = 384; nblk = 128; }
    else if (b < 640) { ten = 3; b0 = 512; nblk = 128; }
    else if (b < 768) { ten = 4; b0 = 640; nblk = 128; }
    else              { ten = 5; b0 = 768; nblk = 768; }
    unsigned int* gh = hist + (long)ten * 16384;
    for (int k = t; k < 16384; k += 256) lh[k] = 0u;
    __syncthreads();
    long i = (long)(b - b0) * 256 + t;
    long stride = (long)nblk * 256;
    if (ten == 0) {
        for (; i < SH / 4; i += stride) {
            float4 v = *(const float4*)(x + i * 4);
            unsigned int u0 = (__builtin_bit_cast(unsigned int, v.x) & 0x7FFFFFFFu) >> 16;
            unsigned int u1 = (__builtin_bit_cast(unsigned int, v.y) & 0x7FFFFFFFu) >> 16;
            unsigned int u2 = (__builtin_bit_cast(unsigned int, v.z) & 0x7FFFFFFFu) >> 16;
            unsigned int u3 = (__builtin_bit_cast(unsigned int, v.w) & 0x7FFFFFFFu) >> 16;
            atomicAdd(&lh[u0 < 16384u ? u0 : 16383u], 1u);
            atomicAdd(&lh[u1 < 16384u ? u1 : 16383u], 1u);
            atomicAdd(&lh[u2 < 16384u ? u2 : 16383u], 1u);
            atomicAdd(&lh[u3 < 16384u ? u3 : 16383u], 1u);
        }
    } else if (ten <= 3) {
        const unsigned short* src = qkv + (size_t)(ten - 1) * SH;
        for (; i < SH / 8; i += stride) {
            ushort8v v = ((const ushort8v*)src)[i];
#pragma unroll
            for (int j = 0; j < 8; ++j) {
                unsigned int u = v[j] & 0x7FFFu;
                atomicAdd(&lh[u < 16384u ? u : 16383u], 1u);
            }
        }
    } else if (ten == 4) {
        for (; i < SH / 8; i += stride) {
            long off = (i >> 9) * KEO + ((i & 511) << 3);
            ushort8v v = *(const ushort8v*)(ob + off);
#pragma unroll
            for (int j = 0; j < 8; ++j) {
                unsigned int u = v[j] & 0x7FFFu;
                atomicAdd(&lh[u < 16384u ? u : 16383u], 1u);
            }
        }
    } else {
        unsigned int zc = 0;
        for (; i < TOTP / 8; i += stride) {
            ushort8v v = ((const ushort8v*)P)[i];
#pragma unroll
            for (int j = 0; j < 8; ++j) {
                unsigned int bb = v[j];
                if (bb == 0) zc++;
                else atomicAdd(&lh[bb < 16384u ? bb : 16383u], 1u);
            }
        }
        if (zc) atomicAdd(&lh[0], zc);
    }
    __syncthreads();
    for (int k = t; k < 16384; k += 256) {
        unsigned int c = lh[k];
        if (c) atomicAdd(&gh[k], c);
    }
}

// ---------------- finish: combine split-K + bias (b<4096) | scan6 (b>=4096) ------
__global__ __launch_bounds__(256) void finish_kernel(
    float* __restrict__ out, const float* __restrict__ part,
    const float* __restrict__ bias, const unsigned int* __restrict__ hist,
    float* __restrict__ out_kth) {
    int b = blockIdx.x;
    int t = threadIdx.x;
    if (b < 4096) {
        long idx = ((long)b * 256 + t) * 4;
        int n = (int)(idx & 4095);
        float4 o = *(float4*)(out + idx);
        float4 p = *(const float4*)(part + idx);
        float4 bb = *(const float4*)(bias + n);
        o.x += p.x + bb.x; o.y += p.y + bb.y; o.z += p.z + bb.z; o.w += p.w + bb.w;
        *(float4*)(out + idx) = o;
        return;
    }
    int ten = b - 4096;
    const unsigned int* h = hist + (long)ten * 16384;
    __shared__ unsigned int partl[256];
    unsigned int s = 0;
    for (int bb = 0; bb < 64; ++bb) s += h[t * 64 + bb];
    partl[t] = s;
    __syncthreads();
    if (t == 0) {
        long k = (ten == 5) ? TOTP / 2 : (long)S_LEN * H_DIM / 2;
        long c = 0;
        int ch = 0;
        for (; ch < 256; ++ch) {
            if (c + (long)partl[ch] >= k) break;
            c += partl[ch];
        }
        int bin = ch * 64;
        for (;; ++bin) {
            unsigned int hv = h[bin];
            if (c + (long)hv >= k) break;
            c += hv;
        }
        int slot = (ten == 4) ? 5 : (ten == 5) ? 4 : ten;
        out_kth[slot] = __builtin_bit_cast(float, (unsigned int)bin << 16);
    }
}

// ==================================================================
extern "C" void kernel_launch(void* const* d_in, const int* in_sizes, int n_in,
                              void* d_out, int out_size, void* d_ws, size_t ws_size,
                              hipStream_t stream) {
    (void)in_sizes; (void)n_in; (void)out_size; (void)ws_size;
    const float* x = (const float*)d_in[0];
    const int*   wcodes[4] = {(const int*)d_in[1], (const int*)d_in[6],
                              (const int*)d_in[11], (const int*)d_in[16]};
    const float* wabs[4]   = {(const float*)d_in[2], (const float*)d_in[7],
                              (const float*)d_in[12], (const float*)d_in[17]};
    const float* bias[4]   = {(const float*)d_in[3], (const float*)d_in[8],
                              (const float*)d_in[13], (const float*)d_in[18]};
    const float* lA[4]     = {(const float*)d_in[4], (const float*)d_in[9],
                              (const float*)d_in[14], (const float*)d_in[19]};
    const float* lB[4]     = {(const float*)d_in[5], (const float*)d_in[10],
                              (const float*)d_in[15], (const float*)d_in[20]};

    char* wp = (char*)d_ws;
    auto alloc = [&](size_t bytes) {
        char* p = wp; wp += (bytes + 255) & ~(size_t)255; return p;
    };
    const size_t SH  = (size_t)S_LEN * H_DIM;       // 4,194,304
    const long   nW  = (long)H_DIM * H_DIM;
    unsigned short* xb_ext = (unsigned short*)alloc((size_t)S_LEN * KE3 * 2);
    unsigned short* qkvb   = (unsigned short*)alloc(3 * SH * 2);  // q,k,v bf16
    unsigned short* vT     = (unsigned short*)alloc(SH * 2);
    unsigned short* ob_ext = (unsigned short*)alloc((size_t)S_LEN * KEO * 2);
    unsigned short* Wd_ext = (unsigned short*)alloc((size_t)H_DIM * KEO * 2);
    float*        opart  = (float*)alloc(SH * 4);
    float*        bias3  = (float*)alloc(3 * H_DIM * 4);
    unsigned int* hist   = (unsigned int*)alloc(6 * 16384 * 4);
    // scores16 (bf16 P, 67 MB) aliases the region that first holds Wqkv_ext (102 MB)
    char* bigbuf = alloc((size_t)3 * H_DIM * KE3 * 2);
    unsigned short* Wqkv_ext = (unsigned short*)bigbuf;
    unsigned short* scores16 = (unsigned short*)bigbuf;

    float* out_final = (float*)d_out;
    float* out_kth   = out_final + SH;

    unsigned short* qb = qkvb;
    unsigned short* kb = qkvb + SH;
    unsigned short* vb = qkvb + 2 * SH;

    // 0) x cast + lora_a
    xcast_lora<<<S_LEN, 256, 0, stream>>>(x, lA[0], lA[1], lA[2], xb_ext);

    // 1) prep: dequants + pads + bias + hist zero
    prep_weights<<<dim3(9600, 4), 256, 0, stream>>>(
        wcodes[0], wcodes[1], wcodes[2], wcodes[3],
        wabs[0], wabs[1], wabs[2], wabs[3],
        lB[0], lB[1], lB[2], lB[3],
        bias[0], bias[1], bias[2],
        Wqkv_ext, Wd_ext, bias3, hist, nW);

    // 2) QKV: ONE z=3 batched GEMM over K=4160
    gemm_qkv<<<dim3(32, 8, 3), 256, 0, stream>>>(xb_ext, Wqkv_ext, qkvb, bias3);

    // 3) scores16 = q.kT / sqrt(128) bf16 (36 tri tiles/head) + v->vT (x>=36 region)
    gemm_scores<<<dim3(40, 1, NHEAD), 256, 0, stream>>>(qb, kb, scores16, vb, vT);

    // 4) softmax in-place bf16, 2 balanced rows per block
    softmax_causal<<<NHEAD * S_LEN / 2, 256, 0, stream>>>(scores16);

    // 5) o = P.v -> ob_ext (bf16, row stride KEO); K limited to bm+128
    gemm_pv<<<dim3(1, 8, NHEAD), 256, 0, stream>>>(scores16, vT, ob_ext);

    // 6) xa_o columns
    lora_ao_kernel<<<S_LEN, 256, 0, stream>>>(ob_ext, lA[3]);

    // 7) O projection: split-K2 (z=2)
    gemm_oproj<<<dim3(32, 8, 2), 256, 0, stream>>>(ob_ext, Wd_ext, out_final, opart);

    // 8) k-th selects: one 6-tensor histogram (hist zeroed in prep)
    hist6<<<1536, 256, 0, stream>>>(x, qkvb, ob_ext, scores16, hist);

    // 9) finish: combine split-K partials + bias, and scan the 6 histograms
    finish_kernel<<<4102, 256, 0, stream>>>(out_final, opart, bias[3], hist, out_kth);
}

// Round 10
// 719.923 us; speedup vs baseline: 1.0848x; 1.0848x over previous
//
#include <hip/hip_runtime.h>

#define S_LEN  1024
#define H_DIM  4096
#define NHEAD  32
#define HEAD_D 128
#define RANK   16
#define KE3    4160   // QKV extended K: 4096 + 3*16 + 16 pad (130 * 32)
#define KEO    4160   // O-proj extended K: 4096 + 16 + 48 pad (65 * 64) — 64-mult for BK=64
#define TOTP   ((long)NHEAD * S_LEN * S_LEN)

typedef __bf16 bf16x8 __attribute__((ext_vector_type(8)));
typedef float  f32x4  __attribute__((ext_vector_type(4)));
typedef unsigned short ushort8v __attribute__((ext_vector_type(8)));

#define GLOAD_LDS16(g, l) __builtin_amdgcn_global_load_lds( \
    (const __attribute__((address_space(1))) unsigned int*)(g), \
    (__attribute__((address_space(3))) unsigned int*)(l), 16, 0, 0)

__device__ const float NF4_TAB[16] = {
    -1.0f, -0.6961928009986877f, -0.5250730514526367f, -0.39491748809814453f,
    -0.28444138169288635f, -0.18477343022823334f, -0.09105003625154495f, 0.0f,
    0.07958029955625534f, 0.16093020141124725f, 0.24611230194568634f,
    0.33791524171829224f, 0.4407098591327667f, 0.5626170039176941f,
    0.7229568362236023f, 1.0f};

__device__ __forceinline__ unsigned short f2bf(float f) {
    unsigned int u = __builtin_bit_cast(unsigned int, f);
    u = (u + 0x7FFFu + ((u >> 16) & 1u)) >> 16;   // RNE
    return (unsigned short)u;
}

__device__ __forceinline__ float bf2f(unsigned short s) {
    return __builtin_bit_cast(float, (unsigned int)s << 16);
}

// ---------------- plain dequant NF4 -> bf16, strided output row ----------------
__device__ __forceinline__ void dequant_body(
    const int* __restrict__ codes, const float* __restrict__ absmax,
    unsigned short* __restrict__ out, long i, int ostride) {
    int4 c0 = *(const int4*)(codes + i);
    int4 c1 = *(const int4*)(codes + i + 4);
    float am = absmax[i >> 6];
    long orow = i >> 12;                 // H_DIM = 4096
    int  col  = (int)(i & 4095);
    ushort8v r;
    r[0] = f2bf(NF4_TAB[c0.x] * am);
    r[1] = f2bf(NF4_TAB[c0.y] * am);
    r[2] = f2bf(NF4_TAB[c0.z] * am);
    r[3] = f2bf(NF4_TAB[c0.w] * am);
    r[4] = f2bf(NF4_TAB[c1.x] * am);
    r[5] = f2bf(NF4_TAB[c1.y] * am);
    r[6] = f2bf(NF4_TAB[c1.z] * am);
    r[7] = f2bf(NF4_TAB[c1.w] * am);
    *(ushort8v*)(out + orow * ostride + col) = r;
}

// -------- x cast + 3x lora_a, one row per block ----
__global__ __launch_bounds__(256) void xcast_lora(
    const float* __restrict__ x, const float* __restrict__ la0,
    const float* __restrict__ la1, const float* __restrict__ la2,
    unsigned short* __restrict__ xb_ext) {
    __shared__ float xs[4096];
    int m = (int)blockIdx.x;
    int tid = threadIdx.x;
    const float* xr = x + (long)m * H_DIM;
    int c = tid * 16;
    float4 f0 = *(const float4*)(xr + c);
    float4 f1 = *(const float4*)(xr + c + 4);
    float4 f2 = *(const float4*)(xr + c + 8);
    float4 f3 = *(const float4*)(xr + c + 12);
    *(float4*)(xs + c)      = f0;
    *(float4*)(xs + c + 4)  = f1;
    *(float4*)(xs + c + 8)  = f2;
    *(float4*)(xs + c + 12) = f3;
    ushort8v r0, r1;
    r0[0] = f2bf(f0.x); r0[1] = f2bf(f0.y); r0[2] = f2bf(f0.z); r0[3] = f2bf(f0.w);
    r0[4] = f2bf(f1.x); r0[5] = f2bf(f1.y); r0[6] = f2bf(f1.z); r0[7] = f2bf(f1.w);
    r1[0] = f2bf(f2.x); r1[1] = f2bf(f2.y); r1[2] = f2bf(f2.z); r1[3] = f2bf(f2.w);
    r1[4] = f2bf(f3.x); r1[5] = f2bf(f3.y); r1[6] = f2bf(f3.z); r1[7] = f2bf(f3.w);
    unsigned short* orow = xb_ext + (long)m * KE3 + c;
    *(ushort8v*)orow = r0;
    *(ushort8v*)(orow + 8) = r1;
    __syncthreads();
    int w = tid >> 6, lane = tid & 63;
    if (w < 3) {
        const float* la = (w == 0) ? la0 : (w == 1) ? la1 : la2;
        float s[16];
#pragma unroll
        for (int r = 0; r < 16; ++r) s[r] = 0.f;
        for (int k = lane; k < H_DIM; k += 64) {
            float xv = xs[k];
            const float4* lr = (const float4*)(la + (long)k * RANK);
            float4 q0 = lr[0], q1 = lr[1], q2 = lr[2], q3 = lr[3];
            s[0] += xv * q0.x;  s[1] += xv * q0.y;  s[2] += xv * q0.z;  s[3] += xv * q0.w;
            s[4] += xv * q1.x;  s[5] += xv * q1.y;  s[6] += xv * q1.z;  s[7] += xv * q1.w;
            s[8] += xv * q2.x;  s[9] += xv * q2.y;  s[10] += xv * q2.z; s[11] += xv * q2.w;
            s[12] += xv * q3.x; s[13] += xv * q3.y; s[14] += xv * q3.z; s[15] += xv * q3.w;
        }
        for (int off = 32; off; off >>= 1)
#pragma unroll
            for (int r = 0; r < 16; ++r) s[r] += __shfl_xor(s[r], off);
        if (lane == 0)
#pragma unroll
            for (int r = 0; r < 16; ++r)
                xb_ext[(long)m * KE3 + 4096 + 16 * w + r] = f2bf(s[r]);
    } else if (lane < 16) {
        // zero the 16 alignment-pad columns [4144,4160)
        xb_ext[(long)m * KE3 + 4144 + lane] = 0;
    }
}

// -------- prep: 4 dequants + lbT pads + bias + hist zero (no LDS) --------
// grid dim3(9600, 4):
//  bx<8192               : dequant main region (all p), one-shot 8 elem/thread
//  p<3,  bx in [8192,9216): lbT/zero pad cols (64/row) + bias gather
//  p==3, bx in [8192,9216): wo pad cols (64/row, KEO=4160)
//  p==1, bx in [9216,9600): zero hist buffer (6*16384 uints)
// NOTE (round 8 lesson): moving the Wd dequant into the QKV GEMM as 192
// grid-stride blocks REGRESSED +65us — a fused BW-region needs the same
// TLP shape as the standalone kernel (2048 one-shot blocks).
__global__ __launch_bounds__(256) void prep_weights(
    const int* __restrict__ c0, const int* __restrict__ c1,
    const int* __restrict__ c2, const int* __restrict__ c3,
    const float* __restrict__ a0, const float* __restrict__ a1,
    const float* __restrict__ a2, const float* __restrict__ a3,
    const float* __restrict__ lb0, const float* __restrict__ lb1,
    const float* __restrict__ lb2, const float* __restrict__ lb3,
    const float* __restrict__ b0, const float* __restrict__ b1,
    const float* __restrict__ b2,
    unsigned short* __restrict__ wqkv, unsigned short* __restrict__ wo,
    float* __restrict__ bias3, unsigned int* __restrict__ hist, long n) {
    int p = blockIdx.y;
    long bx = blockIdx.x;
    int tid = threadIdx.x;
    if (bx < 8192) {
        const int* codes = (p == 0) ? c0 : (p == 1) ? c1 : (p == 2) ? c2 : c3;
        const float* am  = (p == 0) ? a0 : (p == 1) ? a1 : (p == 2) ? a2 : a3;
        long i = (bx * 256 + tid) * 8;
        if (i >= n) return;
        if (p < 3) dequant_body(codes, am, wqkv + (size_t)p * H_DIM * KE3, i, KE3);
        else       dequant_body(codes, am, wo, i, KEO);
        return;
    }
    if (bx < 9216) {
        long g = (bx - 8192) * 256 + tid;
        int row = (int)(g >> 6), c = (int)(g & 63);
        if (p < 3) {
            const float* lb = (p == 0) ? lb0 : (p == 1) ? lb1 : lb2;
            unsigned int r = (unsigned int)(c - 16 * p);
            float v = (r < 16u) ? lb[r * H_DIM + row] : 0.f;
            wqkv[(size_t)p * H_DIM * KE3 + (long)row * KE3 + 4096 + c] = f2bf(v);
            if (g < H_DIM) {
                const float* bp = (p == 0) ? b0 : (p == 1) ? b1 : b2;
                bias3[(size_t)p * H_DIM + g] = bp[g];
            }
            return;
        }
        // p == 3: wo pad cols [4096,4160)
        float v = (c < 16) ? lb3[c * H_DIM + row] : 0.f;
        wo[(long)row * KEO + 4096 + c] = f2bf(v);
        return;
    }
    if (p == 1) {
        long g = (bx - 9216) * 256 + tid;
        if (g < 6 * 16384) hist[g] = 0u;
    }
}

// xa_o = ob @ la_o (bf16 in) -> bf16 cols of ob_ext — ushort8-vectorized x loads
__global__ __launch_bounds__(256) void lora_ao_kernel(
    unsigned short* __restrict__ ob_ext, const float* __restrict__ la) {
    int m = blockIdx.x;
    const unsigned short* xr = ob_ext + (long)m * KEO;
    int tid = threadIdx.x, lane = tid & 63, wid = tid >> 6;
    float s[4] = {0.f, 0.f, 0.f, 0.f};
    for (int k0 = lane * 8; k0 < H_DIM; k0 += 512) {     // 8 iters, 16B/lane
        ushort8v xv8 = *(const ushort8v*)(xr + k0);
#pragma unroll
        for (int j = 0; j < 8; ++j) {
            float xv = bf2f(xv8[j]);
            float4 q = *(const float4*)(la + (long)(k0 + j) * RANK + wid * 4);
            s[0] += xv * q.x; s[1] += xv * q.y;
            s[2] += xv * q.z; s[3] += xv * q.w;
        }
    }
    for (int off = 32; off; off >>= 1)
        for (int r = 0; r < 4; ++r) s[r] += __shfl_down(s[r], off);
    if (lane == 0) {
        for (int r = 0; r < 4; ++r)
            ob_ext[(long)m * KEO + 4096 + wid * 4 + r] = f2bf(s[r]);
        // zero pad cols [4112,4160): 12 per wave
        for (int r = 0; r < 12; ++r)
            ob_ext[(long)m * KEO + 4112 + wid * 12 + r] = 0;
    }
}

// ---------------- bf16 NT GEMM body: C[m][n] = alpha*sum_k A[m][k]*B[n][k] (+bias[n]) --
// BK=64, 128B LDS rows, XOR slot-swizzle (slot ^= row&7) -> conflict-free ds_read_b128.
// Single-buffer 2-barrier structure (measured 848 TF, 0 conflicts — round 5/7).
// NOTE (round 6 lesson): explicit dbuf + 64KB LDS REGRESSED (occupancy 30->16.5%,
// FETCH +40%) — reproduces learn_hip m132. Do not re-attempt at 128² tile.
// NOTE (round 9 lesson): ALL dims/strides MUST be runtime kernel args. Baking
// K=4160 as a device-side literal made the 65-iter K-loop trip count
// compile-time -> unroll -> VGPR 80->88, occupancy 31->16.5%, 127->198us.
// Wrappers below forward their own runtime args; host passes the values.
template<int MODE>
__device__ __forceinline__ void gemm_body(
    const unsigned short* __restrict__ A, const unsigned short* __restrict__ B,
    void* __restrict__ Cv, void* __restrict__ Cv2, const float* __restrict__ bias,
    int K, int lda, int ldb, int ldc,
    long strideA, long strideB, long strideC, float alpha,
    const unsigned short* __restrict__ tsrc, unsigned short* __restrict__ tdst) {
    __shared__ unsigned short As[128][64];   // 16 KB each, 128B rows (8 swizzle slots)
    __shared__ unsigned short Bs[128][64];
    const int tid = threadIdx.x;
    int bm, bn;
    int k0s = 0, k0e = K;
    if (MODE == 1) {
        int i = blockIdx.x;
        if (i >= 36) {
            // transpose region: 128 blocks, 32x32 tiles, padded LDS overlay
            unsigned short (*tl)[33] = (unsigned short(*)[33])&As[0][0];
            int tb = (i - 36) + 4 * blockIdx.z;
            int tx = tid & 31, ty = tid >> 5;           // 8 rows per pass
            for (int tile = tb; tile < 4096; tile += 128) {
                int tc = tile & 127, ts = tile >> 7;
                int c0 = tc * 32, s0 = ts * 32;
                for (int j = 0; j < 32; j += 8)
                    tl[ty + j][tx] = tsrc[(long)(s0 + ty + j) * H_DIM + c0 + tx];
                __syncthreads();
                for (int j = 0; j < 32; j += 8)
                    tdst[(long)(c0 + ty + j) * S_LEN + s0 + tx] = tl[tx][ty + j];
                __syncthreads();
            }
            return;
        }
        int tm = (int)((sqrtf(8.f * i + 1.f) - 1.f) * 0.5f);
        if ((tm + 1) * (tm + 2) / 2 <= i) tm++;
        if (tm * (tm + 1) / 2 > i) tm--;
        int tn = i - tm * (tm + 1) / 2;
        bm = tm * 128; bn = tn * 128;
    } else {
        bm = blockIdx.y * 128; bn = blockIdx.x * 128;
        if (MODE == 2) { int kl = bm + 128; if (kl < k0e) k0e = kl; }
    }
    const unsigned short* Ab = A;
    const unsigned short* Bb = B;
    long coff = 0;
    void* Cuse = Cv;
    if (MODE == 3) {
        int Kh = (K / 2) & ~63;
        k0s = blockIdx.z ? Kh : 0;
        k0e = blockIdx.z ? K : Kh;
        Cuse = blockIdx.z ? Cv2 : Cv;
    } else {
        Ab += (long)blockIdx.z * strideA;
        Bb += (long)blockIdx.z * strideB;
        coff = (long)blockIdx.z * strideC;
    }
    const int lane = tid & 63, wid = tid >> 6;
    const int wm = (wid >> 1) * 64, wn = (wid & 1) * 64;
    // staging: pass p covers LDS rows [p*32 + wid*8, +8); lane -> row l>>3, slot l&7
    const int srow = lane >> 3;
    const int scol = ((lane & 7) ^ srow) << 3;          // pre-swizzled source col
    const int r0 = wid * 8 + srow;
    const unsigned short* gA0 = Ab + (long)(bm + r0) * lda + scol;
    const unsigned short* gB0 = Bb + (long)(bn + r0) * ldb + scol;
    f32x4 acc[4][4] = {};
    const int q = lane >> 4, rr = lane & 15;
    const int colh0 = ((q ^ (rr & 7)) << 3);            // k-half 0 slots (0..3 ^ row)
    const int colh1 = colh0 ^ 32;                       // k-half 1 (bit2 of slot)
    for (int k0 = k0s; k0 < k0e; k0 += 64) {
#pragma unroll
        for (int p = 0; p < 4; ++p) {
            GLOAD_LDS16(gA0 + (long)p * 32 * lda + k0, &As[p * 32 + wid * 8][0]);
            GLOAD_LDS16(gB0 + (long)p * 32 * ldb + k0, &Bs[p * 32 + wid * 8][0]);
        }
        __syncthreads();
        bf16x8 af[4], bfr[4];
#pragma unroll
        for (int i = 0; i < 4; ++i) {
            af[i]  = __builtin_bit_cast(bf16x8, *(const uint4*)&As[wm + i * 16 + rr][colh0]);
            bfr[i] = __builtin_bit_cast(bf16x8, *(const uint4*)&Bs[wn + i * 16 + rr][colh0]);
        }
#pragma unroll
        for (int i = 0; i < 4; ++i)
#pragma unroll
            for (int j = 0; j < 4; ++j)
                acc[i][j] = __builtin_amdgcn_mfma_f32_16x16x32_bf16(
                    af[i], bfr[j], acc[i][j], 0, 0, 0);
#pragma unroll
        for (int i = 0; i < 4; ++i) {
            af[i]  = __builtin_bit_cast(bf16x8, *(const uint4*)&As[wm + i * 16 + rr][colh1]);
            bfr[i] = __builtin_bit_cast(bf16x8, *(const uint4*)&Bs[wn + i * 16 + rr][colh1]);
        }
#pragma unroll
        for (int i = 0; i < 4; ++i)
#pragma unroll
            for (int j = 0; j < 4; ++j)
                acc[i][j] = __builtin_amdgcn_mfma_f32_16x16x32_bf16(
                    af[i], bfr[j], acc[i][j], 0, 0, 0);
        __syncthreads();
    }
    const int cr = (lane >> 4) * 4;
    const int cc = lane & 15;
    float bv[4];
#pragma unroll
    for (int j = 0; j < 4; ++j)
        bv[j] = bias ? bias[(long)blockIdx.z * H_DIM + bn + wn + j * 16 + cc] : 0.f;
    if (MODE != 3) {
        unsigned short* Cb = (unsigned short*)Cuse + coff;
        for (int i = 0; i < 4; ++i)
            for (int j = 0; j < 4; ++j) {
                unsigned short* cp = Cb + (long)(bm + wm + i * 16 + cr) * ldc
                                        + (bn + wn + j * 16 + cc);
                for (int r = 0; r < 4; ++r)
                    cp[(long)r * ldc] = f2bf(acc[i][j][r] * alpha + bv[j]);
            }
    } else {
        float* Cb = (float*)Cuse + coff;
        for (int i = 0; i < 4; ++i)
            for (int j = 0; j < 4; ++j) {
                float* cp = Cb + (long)(bm + wm + i * 16 + cr) * ldc
                               + (bn + wn + j * 16 + cc);
                for (int r = 0; r < 4; ++r)
                    cp[(long)r * ldc] = acc[i][j][r] * alpha + bv[j];
            }
    }
}

// Named wrappers — distinct Kernel_Name per stage; ALL params runtime-forwarded
// (round-9 lesson: do NOT bake dims device-side).
__global__ __launch_bounds__(256) void gemm_qkv(
    const unsigned short* __restrict__ A, const unsigned short* __restrict__ B,
    void* __restrict__ Cv, void* __restrict__ Cv2, const float* __restrict__ bias,
    int K, int lda, int ldb, int ldc,
    long strideA, long strideB, long strideC, float alpha,
    const unsigned short* __restrict__ tsrc, unsigned short* __restrict__ tdst) {
    gemm_body<0>(A, B, Cv, Cv2, bias, K, lda, ldb, ldc,
                 strideA, strideB, strideC, alpha, tsrc, tdst);
}

__global__ __launch_bounds__(256) void gemm_scores(
    const unsigned short* __restrict__ A, const unsigned short* __restrict__ B,
    void* __restrict__ Cv, void* __restrict__ Cv2, const float* __restrict__ bias,
    int K, int lda, int ldb, int ldc,
    long strideA, long strideB, long strideC, float alpha,
    const unsigned short* __restrict__ tsrc, unsigned short* __restrict__ tdst) {
    gemm_body<1>(A, B, Cv, Cv2, bias, K, lda, ldb, ldc,
                 strideA, strideB, strideC, alpha, tsrc, tdst);
}

__global__ __launch_bounds__(256) void gemm_pv(
    const unsigned short* __restrict__ A, const unsigned short* __restrict__ B,
    void* __restrict__ Cv, void* __restrict__ Cv2, const float* __restrict__ bias,
    int K, int lda, int ldb, int ldc,
    long strideA, long strideB, long strideC, float alpha,
    const unsigned short* __restrict__ tsrc, unsigned short* __restrict__ tdst) {
    gemm_body<2>(A, B, Cv, Cv2, bias, K, lda, ldb, ldc,
                 strideA, strideB, strideC, alpha, tsrc, tdst);
}

__global__ __launch_bounds__(256) void gemm_oproj(
    const unsigned short* __restrict__ A, const unsigned short* __restrict__ B,
    void* __restrict__ Cv, void* __restrict__ Cv2, const float* __restrict__ bias,
    int K, int lda, int ldb, int ldc,
    long strideA, long strideB, long strideC, float alpha,
    const unsigned short* __restrict__ tsrc, unsigned short* __restrict__ tdst) {
    gemm_body<3>(A, B, Cv, Cv2, bias, K, lda, ldb, ldc,
                 strideA, strideB, strideC, alpha, tsrc, tdst);
}

// ---------------- causal softmax, bf16 in/out in-place, 2 balanced rows/block ----
__global__ __launch_bounds__(256) void softmax_causal(unsigned short* __restrict__ scores16) {
    int b = blockIdx.x;
    int h = b >> 9, pr = b & 511;
    int tid = threadIdx.x, lane = tid & 63, wid = tid >> 6;
    __shared__ float red[4], red2[4];
    for (int half = 0; half < 2; ++half) {
        int i = half ? (S_LEN - 1 - pr) : pr;
        unsigned short* row = scores16 + ((long)h * S_LEN + i) * S_LEN;
        int L = i + 1;
        float v[4];
        float mx = -1e30f;
        for (int t = 0; t < 4; ++t) {
            int j = tid + (t << 8);
            v[t] = (j < L) ? bf2f(row[j]) : -1e30f;
            mx = fmaxf(mx, v[t]);
        }
        for (int off = 32; off; off >>= 1) mx = fmaxf(mx, __shfl_xor(mx, off));
        if (lane == 0) red[wid] = mx;
        __syncthreads();
        mx = fmaxf(fmaxf(red[0], red[1]), fmaxf(red[2], red[3]));
        float e[4], sum = 0.f;
        for (int t = 0; t < 4; ++t) {
            int j = tid + (t << 8);
            e[t] = (j < L) ? __expf(v[t] - mx) : 0.f;
            sum += e[t];
        }
        for (int off = 32; off; off >>= 1) sum += __shfl_xor(sum, off);
        if (lane == 0) red2[wid] = sum;
        __syncthreads();
        sum = red2[0] + red2[1] + red2[2] + red2[3];
        float inv = 1.f / sum;
        for (int t = 0; t < 4; ++t) {
            int j = tid + (t << 8);
            row[j] = f2bf(e[t] * inv);
        }
        __syncthreads();
    }
}

// ---------------- mega histogram: 6 tensors, flat weighted grid (1536 blocks) ----
// [0,256) x fp32 | [256,384) q | [384,512) k | [512,640) v | [640,768) o | [768,1536) P
__global__ __launch_bounds__(256, 2) void hist6(
    const float* __restrict__ x, const unsigned short* __restrict__ qkv,
    const unsigned short* __restrict__ ob, const unsigned short* __restrict__ P,
    unsigned int* __restrict__ hist) {
    __shared__ unsigned int lh[16384];
    const long SH = (long)S_LEN * H_DIM;
    int t = threadIdx.x;
    int b = blockIdx.x;
    int ten, b0, nblk;
    if (b < 256)      { ten = 0; b0 = 0;   nblk = 256; }
    else if (b < 384) { ten = 1; b0 = 256; nblk = 128; }
    else if (b < 512) { ten = 2; b0 = 384; nblk = 128; }
    else if (b < 640) { ten = 3; b0 = 512; nblk = 128; }
    else if (b < 768) { ten = 4; b0 = 640; nblk = 128; }
    else              { ten = 5; b0 = 768; nblk = 768; }
    unsigned int* gh = hist + (long)ten * 16384;
    for (int k = t; k < 16384; k += 256) lh[k] = 0u;
    __syncthreads();
    long i = (long)(b - b0) * 256 + t;
    long stride = (long)nblk * 256;
    if (ten == 0) {
        for (; i < SH / 4; i += stride) {
            float4 v = *(const float4*)(x + i * 4);
            unsigned int u0 = (__builtin_bit_cast(unsigned int, v.x) & 0x7FFFFFFFu) >> 16;
            unsigned int u1 = (__builtin_bit_cast(unsigned int, v.y) & 0x7FFFFFFFu) >> 16;
            unsigned int u2 = (__builtin_bit_cast(unsigned int, v.z) & 0x7FFFFFFFu) >> 16;
            unsigned int u3 = (__builtin_bit_cast(unsigned int, v.w) & 0x7FFFFFFFu) >> 16;
            atomicAdd(&lh[u0 < 16384u ? u0 : 16383u], 1u);
            atomicAdd(&lh[u1 < 16384u ? u1 : 16383u], 1u);
            atomicAdd(&lh[u2 < 16384u ? u2 : 16383u], 1u);
            atomicAdd(&lh[u3 < 16384u ? u3 : 16383u], 1u);
        }
    } else if (ten <= 3) {
        const unsigned short* src = qkv + (size_t)(ten - 1) * SH;
        for (; i < SH / 8; i += stride) {
            ushort8v v = ((const ushort8v*)src)[i];
#pragma unroll
            for (int j = 0; j < 8; ++j) {
                unsigned int u = v[j] & 0x7FFFu;
                atomicAdd(&lh[u < 16384u ? u : 16383u], 1u);
            }
        }
    } else if (ten == 4) {
        for (; i < SH / 8; i += stride) {
            long off = (i >> 9) * KEO + ((i & 511) << 3);
            ushort8v v = *(const ushort8v*)(ob + off);
#pragma unroll
            for (int j = 0; j < 8; ++j) {
                unsigned int u = v[j] & 0x7FFFu;
                atomicAdd(&lh[u < 16384u ? u : 16383u], 1u);
            }
        }
    } else {
        unsigned int zc = 0;
        for (; i < TOTP / 8; i += stride) {
            ushort8v v = ((const ushort8v*)P)[i];
#pragma unroll
            for (int j = 0; j < 8; ++j) {
                unsigned int bb = v[j];
                if (bb == 0) zc++;
                else atomicAdd(&lh[bb < 16384u ? bb : 16383u], 1u);
            }
        }
        if (zc) atomicAdd(&lh[0], zc);
    }
    __syncthreads();
    for (int k = t; k < 16384; k += 256) {
        unsigned int c = lh[k];
        if (c) atomicAdd(&gh[k], c);
    }
}

// ---------------- finish: combine split-K + bias (b<4096) | scan6 (b>=4096) ------
__global__ __launch_bounds__(256) void finish_kernel(
    float* __restrict__ out, const float* __restrict__ part,
    const float* __restrict__ bias, const unsigned int* __restrict__ hist,
    float* __restrict__ out_kth) {
    int b = blockIdx.x;
    int t = threadIdx.x;
    if (b < 4096) {
        long idx = ((long)b * 256 + t) * 4;
        int n = (int)(idx & 4095);
        float4 o = *(float4*)(out + idx);
        float4 p = *(const float4*)(part + idx);
        float4 bb = *(const float4*)(bias + n);
        o.x += p.x + bb.x; o.y += p.y + bb.y; o.z += p.z + bb.z; o.w += p.w + bb.w;
        *(float4*)(out + idx) = o;
        return;
    }
    int ten = b - 4096;
    const unsigned int* h = hist + (long)ten * 16384;
    __shared__ unsigned int partl[256];
    unsigned int s = 0;
    for (int bb = 0; bb < 64; ++bb) s += h[t * 64 + bb];
    partl[t] = s;
    __syncthreads();
    if (t == 0) {
        long k = (ten == 5) ? TOTP / 2 : (long)S_LEN * H_DIM / 2;
        long c = 0;
        int ch = 0;
        for (; ch < 256; ++ch) {
            if (c + (long)partl[ch] >= k) break;
            c += partl[ch];
        }
        int bin = ch * 64;
        for (;; ++bin) {
            unsigned int hv = h[bin];
            if (c + (long)hv >= k) break;
            c += hv;
        }
        int slot = (ten == 4) ? 5 : (ten == 5) ? 4 : ten;
        out_kth[slot] = __builtin_bit_cast(float, (unsigned int)bin << 16);
    }
}

// ==================================================================
extern "C" void kernel_launch(void* const* d_in, const int* in_sizes, int n_in,
                              void* d_out, int out_size, void* d_ws, size_t ws_size,
                              hipStream_t stream) {
    (void)in_sizes; (void)n_in; (void)out_size; (void)ws_size;
    const float* x = (const float*)d_in[0];
    const int*   wcodes[4] = {(const int*)d_in[1], (const int*)d_in[6],
                              (const int*)d_in[11], (const int*)d_in[16]};
    const float* wabs[4]   = {(const float*)d_in[2], (const float*)d_in[7],
                              (const float*)d_in[12], (const float*)d_in[17]};
    const float* bias[4]   = {(const float*)d_in[3], (const float*)d_in[8],
                              (const float*)d_in[13], (const float*)d_in[18]};
    const float* lA[4]     = {(const float*)d_in[4], (const float*)d_in[9],
                              (const float*)d_in[14], (const float*)d_in[19]};
    const float* lB[4]     = {(const float*)d_in[5], (const float*)d_in[10],
                              (const float*)d_in[15], (const float*)d_in[20]};

    char* wp = (char*)d_ws;
    auto alloc = [&](size_t bytes) {
        char* p = wp; wp += (bytes + 255) & ~(size_t)255; return p;
    };
    const size_t SH  = (size_t)S_LEN * H_DIM;       // 4,194,304
    const long   nW  = (long)H_DIM * H_DIM;
    unsigned short* xb_ext = (unsigned short*)alloc((size_t)S_LEN * KE3 * 2);
    unsigned short* qkvb   = (unsigned short*)alloc(3 * SH * 2);  // q,k,v bf16
    unsigned short* vT     = (unsigned short*)alloc(SH * 2);
    unsigned short* ob_ext = (unsigned short*)alloc((size_t)S_LEN * KEO * 2);
    unsigned short* Wd_ext = (unsigned short*)alloc((size_t)H_DIM * KEO * 2);
    float*        opart  = (float*)alloc(SH * 4);
    float*        bias3  = (float*)alloc(3 * H_DIM * 4);
    unsigned int* hist   = (unsigned int*)alloc(6 * 16384 * 4);
    // scores16 (bf16 P, 67 MB) aliases the region that first holds Wqkv_ext (102 MB)
    char* bigbuf = alloc((size_t)3 * H_DIM * KE3 * 2);
    unsigned short* Wqkv_ext = (unsigned short*)bigbuf;
    unsigned short* scores16 = (unsigned short*)bigbuf;

    float* out_final = (float*)d_out;
    float* out_kth   = out_final + SH;

    unsigned short* qb = qkvb;
    unsigned short* kb = qkvb + SH;
    unsigned short* vb = qkvb + 2 * SH;

    // 0) x cast + lora_a
    xcast_lora<<<S_LEN, 256, 0, stream>>>(x, lA[0], lA[1], lA[2], xb_ext);

    // 1) prep: dequants + pads + bias + hist zero
    prep_weights<<<dim3(9600, 4), 256, 0, stream>>>(
        wcodes[0], wcodes[1], wcodes[2], wcodes[3],
        wabs[0], wabs[1], wabs[2], wabs[3],
        lB[0], lB[1], lB[2], lB[3],
        bias[0], bias[1], bias[2],
        Wqkv_ext, Wd_ext, bias3, hist, nW);

    // 2) QKV: ONE z=3 batched GEMM over K=4160 (runtime args — round-9 lesson)
    gemm_qkv<<<dim3(32, 8, 3), 256, 0, stream>>>(
        xb_ext, Wqkv_ext, qkvb, nullptr, bias3, KE3, KE3, KE3, H_DIM,
        0, (long)H_DIM * KE3, (long)SH, 1.0f, nullptr, nullptr);

    // 3) scores16 = q.kT / sqrt(128) bf16 (36 tri tiles/head) + v->vT (x>=36 region)
    gemm_scores<<<dim3(40, 1, NHEAD), 256, 0, stream>>>(
        qb, kb, scores16, nullptr, nullptr, HEAD_D, H_DIM, H_DIM, S_LEN,
        128, 128, (long)S_LEN * S_LEN, 0.08838834764831845f, vb, vT);

    // 4) softmax in-place bf16, 2 balanced rows per block
    softmax_causal<<<NHEAD * S_LEN / 2, 256, 0, stream>>>(scores16);

    // 5) o = P.v -> ob_ext (bf16, row stride KEO); K limited to bm+128
    gemm_pv<<<dim3(1, 8, NHEAD), 256, 0, stream>>>(
        scores16, vT, ob_ext, nullptr, nullptr, S_LEN,
        S_LEN, S_LEN, KEO,
        (long)S_LEN * S_LEN, (long)HEAD_D * S_LEN, 128, 1.0f, nullptr, nullptr);

    // 6) xa_o columns
    lora_ao_kernel<<<S_LEN, 256, 0, stream>>>(ob_ext, lA[3]);

    // 7) O projection: split-K2 (z=2)
    gemm_oproj<<<dim3(32, 8, 2), 256, 0, stream>>>(
        ob_ext, Wd_ext, out_final, opart, nullptr, KEO, KEO, KEO, H_DIM,
        0, 0, 0, 1.0f, nullptr, nullptr);

    // 8) k-th selects: one 6-tensor histogram (hist zeroed in prep)
    hist6<<<1536, 256, 0, stream>>>(x, qkvb, ob_ext, scores16, hist);

    // 9) finish: combine split-K partials + bias, and scan the 6 histograms
    finish_kernel<<<4102, 256, 0, stream>>>(out_final, opart, bias[3], hist, out_kth);
}

// Round 13
// 713.234 us; speedup vs baseline: 1.0950x; 1.0094x over previous
//
#include <hip/hip_runtime.h>

#define S_LEN  1024
#define H_DIM  4096
#define NHEAD  32
#define HEAD_D 128
#define RANK   16
#define KE3    4160   // QKV extended K: 4096 + 3*16 + 16 pad (130 * 32)
#define KEO    4160   // O-proj extended K: 4096 + 16 + 48 pad (65 * 64) — 64-mult for BK=64
#define TOTP   ((long)NHEAD * S_LEN * S_LEN)

typedef __bf16 bf16x8 __attribute__((ext_vector_type(8)));
typedef float  f32x4  __attribute__((ext_vector_type(4)));
typedef unsigned short ushort8v __attribute__((ext_vector_type(8)));

#define GLOAD_LDS16(g, l) __builtin_amdgcn_global_load_lds( \
    (const __attribute__((address_space(1))) unsigned int*)(g), \
    (__attribute__((address_space(3))) unsigned int*)(l), 16, 0, 0)

__device__ const float NF4_TAB[16] = {
    -1.0f, -0.6961928009986877f, -0.5250730514526367f, -0.39491748809814453f,
    -0.28444138169288635f, -0.18477343022823334f, -0.09105003625154495f, 0.0f,
    0.07958029955625534f, 0.16093020141124725f, 0.24611230194568634f,
    0.33791524171829224f, 0.4407098591327667f, 0.5626170039176941f,
    0.7229568362236023f, 1.0f};

__device__ __forceinline__ unsigned short f2bf(float f) {
    unsigned int u = __builtin_bit_cast(unsigned int, f);
    u = (u + 0x7FFFu + ((u >> 16) & 1u)) >> 16;   // RNE
    return (unsigned short)u;
}

__device__ __forceinline__ float bf2f(unsigned short s) {
    return __builtin_bit_cast(float, (unsigned int)s << 16);
}

// ---------------- plain dequant NF4 -> bf16, strided output row ----------------
__device__ __forceinline__ void dequant_body(
    const int* __restrict__ codes, const float* __restrict__ absmax,
    unsigned short* __restrict__ out, long i, int ostride) {
    int4 c0 = *(const int4*)(codes + i);
    int4 c1 = *(const int4*)(codes + i + 4);
    float am = absmax[i >> 6];
    long orow = i >> 12;                 // H_DIM = 4096
    int  col  = (int)(i & 4095);
    ushort8v r;
    r[0] = f2bf(NF4_TAB[c0.x] * am);
    r[1] = f2bf(NF4_TAB[c0.y] * am);
    r[2] = f2bf(NF4_TAB[c0.z] * am);
    r[3] = f2bf(NF4_TAB[c0.w] * am);
    r[4] = f2bf(NF4_TAB[c1.x] * am);
    r[5] = f2bf(NF4_TAB[c1.y] * am);
    r[6] = f2bf(NF4_TAB[c1.z] * am);
    r[7] = f2bf(NF4_TAB[c1.w] * am);
    *(ushort8v*)(out + orow * ostride + col) = r;
}

// -------- x cast + 3x lora_a, one row per block ----
__global__ __launch_bounds__(256) void xcast_lora(
    const float* __restrict__ x, const float* __restrict__ la0,
    const float* __restrict__ la1, const float* __restrict__ la2,
    unsigned short* __restrict__ xb_ext) {
    __shared__ float xs[4096];
    int m = (int)blockIdx.x;
    int tid = threadIdx.x;
    const float* xr = x + (long)m * H_DIM;
    int c = tid * 16;
    float4 f0 = *(const float4*)(xr + c);
    float4 f1 = *(const float4*)(xr + c + 4);
    float4 f2 = *(const float4*)(xr + c + 8);
    float4 f3 = *(const float4*)(xr + c + 12);
    *(float4*)(xs + c)      = f0;
    *(float4*)(xs + c + 4)  = f1;
    *(float4*)(xs + c + 8)  = f2;
    *(float4*)(xs + c + 12) = f3;
    ushort8v r0, r1;
    r0[0] = f2bf(f0.x); r0[1] = f2bf(f0.y); r0[2] = f2bf(f0.z); r0[3] = f2bf(f0.w);
    r0[4] = f2bf(f1.x); r0[5] = f2bf(f1.y); r0[6] = f2bf(f1.z); r0[7] = f2bf(f1.w);
    r1[0] = f2bf(f2.x); r1[1] = f2bf(f2.y); r1[2] = f2bf(f2.z); r1[3] = f2bf(f2.w);
    r1[4] = f2bf(f3.x); r1[5] = f2bf(f3.y); r1[6] = f2bf(f3.z); r1[7] = f2bf(f3.w);
    unsigned short* orow = xb_ext + (long)m * KE3 + c;
    *(ushort8v*)orow = r0;
    *(ushort8v*)(orow + 8) = r1;
    __syncthreads();
    int w = tid >> 6, lane = tid & 63;
    if (w < 3) {
        const float* la = (w == 0) ? la0 : (w == 1) ? la1 : la2;
        float s[16];
#pragma unroll
        for (int r = 0; r < 16; ++r) s[r] = 0.f;
        for (int k = lane; k < H_DIM; k += 64) {
            float xv = xs[k];
            const float4* lr = (const float4*)(la + (long)k * RANK);
            float4 q0 = lr[0], q1 = lr[1], q2 = lr[2], q3 = lr[3];
            s[0] += xv * q0.x;  s[1] += xv * q0.y;  s[2] += xv * q0.z;  s[3] += xv * q0.w;
            s[4] += xv * q1.x;  s[5] += xv * q1.y;  s[6] += xv * q1.z;  s[7] += xv * q1.w;
            s[8] += xv * q2.x;  s[9] += xv * q2.y;  s[10] += xv * q2.z; s[11] += xv * q2.w;
            s[12] += xv * q3.x; s[13] += xv * q3.y; s[14] += xv * q3.z; s[15] += xv * q3.w;
        }
        for (int off = 32; off; off >>= 1)
#pragma unroll
            for (int r = 0; r < 16; ++r) s[r] += __shfl_xor(s[r], off);
        if (lane == 0)
#pragma unroll
            for (int r = 0; r < 16; ++r)
                xb_ext[(long)m * KE3 + 4096 + 16 * w + r] = f2bf(s[r]);
    } else if (lane < 16) {
        // zero the 16 alignment-pad columns [4144,4160)
        xb_ext[(long)m * KE3 + 4144 + lane] = 0;
    }
}

// -------- prep: 4 dequants + lbT pads + bias + hist zero (no LDS) --------
// grid dim3(9600, 4):
//  bx<8192               : dequant main region (all p), one-shot 8 elem/thread
//  p<3,  bx in [8192,9216): lbT/zero pad cols (64/row) + bias gather
//  p==3, bx in [8192,9216): wo pad cols (64/row, KEO=4160)
//  p==1, bx in [9216,9600): zero hist buffer (6*16384 uints)
// NOTE (round 8 lesson): moving the Wd dequant into the QKV GEMM as 192
// grid-stride blocks REGRESSED +65us — a fused BW-region needs the same
// TLP shape as the standalone kernel (2048 one-shot blocks).
__global__ __launch_bounds__(256) void prep_weights(
    const int* __restrict__ c0, const int* __restrict__ c1,
    const int* __restrict__ c2, const int* __restrict__ c3,
    const float* __restrict__ a0, const float* __restrict__ a1,
    const float* __restrict__ a2, const float* __restrict__ a3,
    const float* __restrict__ lb0, const float* __restrict__ lb1,
    const float* __restrict__ lb2, const float* __restrict__ lb3,
    const float* __restrict__ b0, const float* __restrict__ b1,
    const float* __restrict__ b2,
    unsigned short* __restrict__ wqkv, unsigned short* __restrict__ wo,
    float* __restrict__ bias3, unsigned int* __restrict__ hist, long n) {
    int p = blockIdx.y;
    long bx = blockIdx.x;
    int tid = threadIdx.x;
    if (bx < 8192) {
        const int* codes = (p == 0) ? c0 : (p == 1) ? c1 : (p == 2) ? c2 : c3;
        const float* am  = (p == 0) ? a0 : (p == 1) ? a1 : (p == 2) ? a2 : a3;
        long i = (bx * 256 + tid) * 8;
        if (i >= n) return;
        if (p < 3) dequant_body(codes, am, wqkv + (size_t)p * H_DIM * KE3, i, KE3);
        else       dequant_body(codes, am, wo, i, KEO);
        return;
    }
    if (bx < 9216) {
        long g = (bx - 8192) * 256 + tid;
        int row = (int)(g >> 6), c = (int)(g & 63);
        if (p < 3) {
            const float* lb = (p == 0) ? lb0 : (p == 1) ? lb1 : lb2;
            unsigned int r = (unsigned int)(c - 16 * p);
            float v = (r < 16u) ? lb[r * H_DIM + row] : 0.f;
            wqkv[(size_t)p * H_DIM * KE3 + (long)row * KE3 + 4096 + c] = f2bf(v);
            if (g < H_DIM) {
                const float* bp = (p == 0) ? b0 : (p == 1) ? b1 : b2;
                bias3[(size_t)p * H_DIM + g] = bp[g];
            }
            return;
        }
        // p == 3: wo pad cols [4096,4160)
        float v = (c < 16) ? lb3[c * H_DIM + row] : 0.f;
        wo[(long)row * KEO + 4096 + c] = f2bf(v);
        return;
    }
    if (p == 1) {
        long g = (bx - 9216) * 256 + tid;
        if (g < 6 * 16384) hist[g] = 0u;
    }
}

// xa_o = ob @ la_o (bf16 in) -> bf16 cols of ob_ext — ushort8-vectorized x loads
__global__ __launch_bounds__(256) void lora_ao_kernel(
    unsigned short* __restrict__ ob_ext, const float* __restrict__ la) {
    int m = blockIdx.x;
    const unsigned short* xr = ob_ext + (long)m * KEO;
    int tid = threadIdx.x, lane = tid & 63, wid = tid >> 6;
    float s[4] = {0.f, 0.f, 0.f, 0.f};
    for (int k0 = lane * 8; k0 < H_DIM; k0 += 512) {     // 8 iters, 16B/lane
        ushort8v xv8 = *(const ushort8v*)(xr + k0);
#pragma unroll
        for (int j = 0; j < 8; ++j) {
            float xv = bf2f(xv8[j]);
            float4 q = *(const float4*)(la + (long)(k0 + j) * RANK + wid * 4);
            s[0] += xv * q.x; s[1] += xv * q.y;
            s[2] += xv * q.z; s[3] += xv * q.w;
        }
    }
    for (int off = 32; off; off >>= 1)
        for (int r = 0; r < 4; ++r) s[r] += __shfl_down(s[r], off);
    if (lane == 0) {
        for (int r = 0; r < 4; ++r)
            ob_ext[(long)m * KEO + 4096 + wid * 4 + r] = f2bf(s[r]);
        // zero pad cols [4112,4160): 12 per wave
        for (int r = 0; r < 12; ++r)
            ob_ext[(long)m * KEO + 4112 + wid * 12 + r] = 0;
    }
}

// ---------------- bf16 NT GEMM body: C[m][n] = alpha*sum_k A[m][k]*B[n][k] (+bias[n]) --
// BK=64, 128B LDS rows, XOR slot-swizzle (slot ^= row&7) -> conflict-free ds_read_b128.
// Single-buffer 2-barrier structure (measured 848 TF, 0 conflicts — round 5/7/10).
// NOTE (round 6 lesson): explicit dbuf + 64KB LDS REGRESSED (occupancy 30->16.5%,
// FETCH +40%) — reproduces learn_hip m132. Do not re-attempt at 128² tile.
// NOTE (round 9 lesson): ALL dims/strides MUST be runtime kernel args. Baking
// K=4160 as a device-side literal unrolled the 65-iter K-loop -> VGPR 80->88,
// occupancy 31->16.5%, 127->198us.
// MODE 0: plain batched (z). MODE 1: causal triangular grid (x<36: tri idx, z=head;
//         x in [36,40): v->vT transpose region). MODE 2: batched + K limited to
//         bm+128 (causal PV). MODE 3: split-K3 (z thirds -> Cv/Cv2/tdst, f32 out).
template<int MODE>
__device__ __forceinline__ void gemm_body(
    const unsigned short* __restrict__ A, const unsigned short* __restrict__ B,
    void* __restrict__ Cv, void* __restrict__ Cv2, const float* __restrict__ bias,
    int K, int lda, int ldb, int ldc,
    long strideA, long strideB, long strideC, float alpha,
    const unsigned short* __restrict__ tsrc, unsigned short* __restrict__ tdst) {
    __shared__ unsigned short As[128][64];   // 16 KB each, 128B rows (8 swizzle slots)
    __shared__ unsigned short Bs[128][64];
    const int tid = threadIdx.x;
    int bm, bn;
    int k0s = 0, k0e = K;
    if (MODE == 1) {
        int i = blockIdx.x;
        if (i >= 36) {
            // transpose region: 128 blocks, 32x32 tiles, padded LDS overlay
            unsigned short (*tl)[33] = (unsigned short(*)[33])&As[0][0];
            int tb = (i - 36) + 4 * blockIdx.z;
            int tx = tid & 31, ty = tid >> 5;           // 8 rows per pass
            for (int tile = tb; tile < 4096; tile += 128) {
                int tc = tile & 127, ts = tile >> 7;
                int c0 = tc * 32, s0 = ts * 32;
                for (int j = 0; j < 32; j += 8)
                    tl[ty + j][tx] = tsrc[(long)(s0 + ty + j) * H_DIM + c0 + tx];
                __syncthreads();
                for (int j = 0; j < 32; j += 8)
                    tdst[(long)(c0 + ty + j) * S_LEN + s0 + tx] = tl[tx][ty + j];
                __syncthreads();
            }
            return;
        }
        int tm = (int)((sqrtf(8.f * i + 1.f) - 1.f) * 0.5f);
        if ((tm + 1) * (tm + 2) / 2 <= i) tm++;
        if (tm * (tm + 1) / 2 > i) tm--;
        int tn = i - tm * (tm + 1) / 2;
        bm = tm * 128; bn = tn * 128;
    } else {
        bm = blockIdx.y * 128; bn = blockIdx.x * 128;
        if (MODE == 2) { int kl = bm + 128; if (kl < k0e) k0e = kl; }
    }
    const unsigned short* Ab = A;
    const unsigned short* Bb = B;
    long coff = 0;
    void* Cuse = Cv;
    if (MODE == 3) {
        int Kq = (K / 3) & ~63;
        k0s = (int)blockIdx.z * Kq;
        k0e = (blockIdx.z == 2) ? K : k0s + Kq;
        Cuse = (blockIdx.z == 0) ? Cv : (blockIdx.z == 1) ? Cv2 : (void*)tdst;
    } else {
        Ab += (long)blockIdx.z * strideA;
        Bb += (long)blockIdx.z * strideB;
        coff = (long)blockIdx.z * strideC;
    }
    const int lane = tid & 63, wid = tid >> 6;
    const int wm = (wid >> 1) * 64, wn = (wid & 1) * 64;
    // staging: pass p covers LDS rows [p*32 + wid*8, +8); lane -> row l>>3, slot l&7
    const int srow = lane >> 3;
    const int scol = ((lane & 7) ^ srow) << 3;          // pre-swizzled source col
    const int r0 = wid * 8 + srow;
    const unsigned short* gA0 = Ab + (long)(bm + r0) * lda + scol;
    const unsigned short* gB0 = Bb + (long)(bn + r0) * ldb + scol;
    f32x4 acc[4][4] = {};
    const int q = lane >> 4, rr = lane & 15;
    const int colh0 = ((q ^ (rr & 7)) << 3);            // k-half 0 slots (0..3 ^ row)
    const int colh1 = colh0 ^ 32;                       // k-half 1 (bit2 of slot)
    for (int k0 = k0s; k0 < k0e; k0 += 64) {
#pragma unroll
        for (int p = 0; p < 4; ++p) {
            GLOAD_LDS16(gA0 + (long)p * 32 * lda + k0, &As[p * 32 + wid * 8][0]);
            GLOAD_LDS16(gB0 + (long)p * 32 * ldb + k0, &Bs[p * 32 + wid * 8][0]);
        }
        __syncthreads();
        bf16x8 af[4], bfr[4];
#pragma unroll
        for (int i = 0; i < 4; ++i) {
            af[i]  = __builtin_bit_cast(bf16x8, *(const uint4*)&As[wm + i * 16 + rr][colh0]);
            bfr[i] = __builtin_bit_cast(bf16x8, *(const uint4*)&Bs[wn + i * 16 + rr][colh0]);
        }
#pragma unroll
        for (int i = 0; i < 4; ++i)
#pragma unroll
            for (int j = 0; j < 4; ++j)
                acc[i][j] = __builtin_amdgcn_mfma_f32_16x16x32_bf16(
                    af[i], bfr[j], acc[i][j], 0, 0, 0);
#pragma unroll
        for (int i = 0; i < 4; ++i) {
            af[i]  = __builtin_bit_cast(bf16x8, *(const uint4*)&As[wm + i * 16 + rr][colh1]);
            bfr[i] = __builtin_bit_cast(bf16x8, *(const uint4*)&Bs[wn + i * 16 + rr][colh1]);
        }
#pragma unroll
        for (int i = 0; i < 4; ++i)
#pragma unroll
            for (int j = 0; j < 4; ++j)
                acc[i][j] = __builtin_amdgcn_mfma_f32_16x16x32_bf16(
                    af[i], bfr[j], acc[i][j], 0, 0, 0);
        __syncthreads();
    }
    const int cr = (lane >> 4) * 4;
    const int cc = lane & 15;
    float bv[4];
#pragma unroll
    for (int j = 0; j < 4; ++j)
        bv[j] = bias ? bias[(long)blockIdx.z * H_DIM + bn + wn + j * 16 + cc] : 0.f;
    if (MODE != 3) {
        unsigned short* Cb = (unsigned short*)Cuse + coff;
        for (int i = 0; i < 4; ++i)
            for (int j = 0; j < 4; ++j) {
                unsigned short* cp = Cb + (long)(bm + wm + i * 16 + cr) * ldc
                                        + (bn + wn + j * 16 + cc);
                for (int r = 0; r < 4; ++r)
                    cp[(long)r * ldc] = f2bf(acc[i][j][r] * alpha + bv[j]);
            }
    } else {
        float* Cb = (float*)Cuse + coff;
        for (int i = 0; i < 4; ++i)
            for (int j = 0; j < 4; ++j) {
                float* cp = Cb + (long)(bm + wm + i * 16 + cr) * ldc
                               + (bn + wn + j * 16 + cc);
                for (int r = 0; r < 4; ++r)
                    cp[(long)r * ldc] = acc[i][j][r] * alpha + bv[j];
            }
    }
}

// Named wrappers — distinct Kernel_Name per stage; ALL params runtime-forwarded
// (round-9 lesson: do NOT bake dims device-side).
__global__ __launch_bounds__(256) void gemm_qkv(
    const unsigned short* __restrict__ A, const unsigned short* __restrict__ B,
    void* __restrict__ Cv, void* __restrict__ Cv2, const float* __restrict__ bias,
    int K, int lda, int ldb, int ldc,
    long strideA, long strideB, long strideC, float alpha,
    const unsigned short* __restrict__ tsrc, unsigned short* __restrict__ tdst) {
    gemm_body<0>(A, B, Cv, Cv2, bias, K, lda, ldb, ldc,
                 strideA, strideB, strideC, alpha, tsrc, tdst);
}

__global__ __launch_bounds__(256) void gemm_scores(
    const unsigned short* __restrict__ A, const unsigned short* __restrict__ B,
    void* __restrict__ Cv, void* __restrict__ Cv2, const float* __restrict__ bias,
    int K, int lda, int ldb, int ldc,
    long strideA, long strideB, long strideC, float alpha,
    const unsigned short* __restrict__ tsrc, unsigned short* __restrict__ tdst) {
    gemm_body<1>(A, B, Cv, Cv2, bias, K, lda, ldb, ldc,
                 strideA, strideB, strideC, alpha, tsrc, tdst);
}

__global__ __launch_bounds__(256) void gemm_pv(
    const unsigned short* __restrict__ A, const unsigned short* __restrict__ B,
    void* __restrict__ Cv, void* __restrict__ Cv2, const float* __restrict__ bias,
    int K, int lda, int ldb, int ldc,
    long strideA, long strideB, long strideC, float alpha,
    const unsigned short* __restrict__ tsrc, unsigned short* __restrict__ tdst) {
    gemm_body<2>(A, B, Cv, Cv2, bias, K, lda, ldb, ldc,
                 strideA, strideB, strideC, alpha, tsrc, tdst);
}

__global__ __launch_bounds__(256) void gemm_oproj(
    const unsigned short* __restrict__ A, const unsigned short* __restrict__ B,
    void* __restrict__ Cv, void* __restrict__ Cv2, const float* __restrict__ bias,
    int K, int lda, int ldb, int ldc,
    long strideA, long strideB, long strideC, float alpha,
    const unsigned short* __restrict__ tsrc, unsigned short* __restrict__ tdst) {
    gemm_body<3>(A, B, Cv, Cv2, bias, K, lda, ldb, ldc,
                 strideA, strideB, strideC, alpha, tsrc, tdst);
}

// ---------------- causal softmax, bf16 in/out in-place, vectorized (G13) ----------
// Block = 2 balanced rows processed CONCURRENTLY: warps 0-1 -> row pr,
// warps 2-3 -> row S-1-pr. 128 threads/row x ushort8v chunks (16B/lane) replace
// the old scalar 2B loads/stores (8x fewer memory instructions).
__global__ __launch_bounds__(256) void softmax_causal(unsigned short* __restrict__ scores16) {
    int b = blockIdx.x;
    int h = b >> 9, pr = b & 511;
    int tid = threadIdx.x, lane = tid & 63, wid = tid >> 6;
    int rsel = tid >> 7;                    // 0: row pr, 1: row S-1-pr
    int c = (tid & 127) << 3;               // chunk start col (0..1016)
    __shared__ float red[4], red2[4];
    int i = rsel ? (S_LEN - 1 - pr) : pr;
    unsigned short* row = scores16 + ((long)h * S_LEN + i) * S_LEN;
    int L = i + 1;
    ushort8v v8 = *(const ushort8v*)(row + c);
    float v[8];
    float mx = -1e30f;
#pragma unroll
    for (int j = 0; j < 8; ++j) {
        v[j] = (c + j < L) ? bf2f(v8[j]) : -1e30f;
        mx = fmaxf(mx, v[j]);
    }
    for (int off = 32; off; off >>= 1) mx = fmaxf(mx, __shfl_xor(mx, off));
    if (lane == 0) red[wid] = mx;
    __syncthreads();
    mx = rsel ? fmaxf(red[2], red[3]) : fmaxf(red[0], red[1]);
    float e[8], sum = 0.f;
#pragma unroll
    for (int j = 0; j < 8; ++j) {
        e[j] = (c + j < L) ? __expf(v[j] - mx) : 0.f;
        sum += e[j];
    }
    for (int off = 32; off; off >>= 1) sum += __shfl_xor(sum, off);
    if (lane == 0) red2[wid] = sum;
    __syncthreads();
    sum = rsel ? (red2[2] + red2[3]) : (red2[0] + red2[1]);
    float inv = 1.f / sum;
    ushort8v o8;
#pragma unroll
    for (int j = 0; j < 8; ++j) o8[j] = f2bf(e[j] * inv);
    *(ushort8v*)(row + c) = o8;
}

// ---------------- mega histogram: 6 tensors, flat weighted grid (1536 blocks) ----
// [0,256) x fp32 | [256,384) q | [384,512) k | [512,640) v | [640,768) o | [768,1536) P
__global__ __launch_bounds__(256, 2) void hist6(
    const float* __restrict__ x, const unsigned short* __restrict__ qkv,
    const unsigned short* __restrict__ ob, const unsigned short* __restrict__ P,
    unsigned int* __restrict__ hist) {
    __shared__ unsigned int lh[16384];
    const long SH = (long)S_LEN * H_DIM;
    int t = threadIdx.x;
    int b = blockIdx.x;
    int ten, b0, nblk;
    if (b < 256)      { ten = 0; b0 = 0;   nblk = 256; }
    else if (b < 384) { ten = 1; b0 = 256; nblk = 128; }
    else if (b < 512) { ten = 2; b0 = 384; nblk = 128; }
    else if (b < 640) { ten = 3; b0 = 512; nblk = 128; }
    else if (b < 768) { ten = 4; b0 = 640; nblk = 128; }
    else              { ten = 5; b0 = 768; nblk = 768; }
    unsigned int* gh = hist + (long)ten * 16384;
    for (int k = t; k < 16384; k += 256) lh[k] = 0u;
    __syncthreads();
    long i = (long)(b - b0) * 256 + t;
    long stride = (long)nblk * 256;
    if (ten == 0) {
        for (; i < SH / 4; i += stride) {
            float4 v = *(const float4*)(x + i * 4);
            unsigned int u0 = (__builtin_bit_cast(unsigned int, v.x) & 0x7FFFFFFFu) >> 16;
            unsigned int u1 = (__builtin_bit_cast(unsigned int, v.y) & 0x7FFFFFFFu) >> 16;
            unsigned int u2 = (__builtin_bit_cast(unsigned int, v.z) & 0x7FFFFFFFu) >> 16;
            unsigned int u3 = (__builtin_bit_cast(unsigned int, v.w) & 0x7FFFFFFFu) >> 16;
            atomicAdd(&lh[u0 < 16384u ? u0 : 16383u], 1u);
            atomicAdd(&lh[u1 < 16384u ? u1 : 16383u], 1u);
            atomicAdd(&lh[u2 < 16384u ? u2 : 16383u], 1u);
            atomicAdd(&lh[u3 < 16384u ? u3 : 16383u], 1u);
        }
    } else if (ten <= 3) {
        const unsigned short* src = qkv + (size_t)(ten - 1) * SH;
        for (; i < SH / 8; i += stride) {
            ushort8v v = ((const ushort8v*)src)[i];
#pragma unroll
            for (int j = 0; j < 8; ++j) {
                unsigned int u = v[j] & 0x7FFFu;
                atomicAdd(&lh[u < 16384u ? u : 16383u], 1u);
            }
        }
    } else if (ten == 4) {
        for (; i < SH / 8; i += stride) {
            long off = (i >> 9) * KEO + ((i & 511) << 3);
            ushort8v v = *(const ushort8v*)(ob + off);
#pragma unroll
            for (int j = 0; j < 8; ++j) {
                unsigned int u = v[j] & 0x7FFFu;
                atomicAdd(&lh[u < 16384u ? u : 16383u], 1u);
            }
        }
    } else {
        unsigned int zc = 0;
        for (; i < TOTP / 8; i += stride) {
            ushort8v v = ((const ushort8v*)P)[i];
#pragma unroll
            for (int j = 0; j < 8; ++j) {
                unsigned int bb = v[j];
                if (bb == 0) zc++;
                else atomicAdd(&lh[bb < 16384u ? bb : 16383u], 1u);
            }
        }
        if (zc) atomicAdd(&lh[0], zc);
    }
    __syncthreads();
    for (int k = t; k < 16384; k += 256) {
        unsigned int c = lh[k];
        if (c) atomicAdd(&gh[k], c);
    }
}

// ---------------- finish: combine split-K3 + bias (b<4096) | scan6 (b>=4096) ------
__global__ __launch_bounds__(256) void finish_kernel(
    float* __restrict__ out, const float* __restrict__ part,
    const float* __restrict__ part2,
    const float* __restrict__ bias, const unsigned int* __restrict__ hist,
    float* __restrict__ out_kth) {
    int b = blockIdx.x;
    int t = threadIdx.x;
    if (b < 4096) {
        long idx = ((long)b * 256 + t) * 4;
        int n = (int)(idx & 4095);
        float4 o = *(float4*)(out + idx);
        float4 p = *(const float4*)(part + idx);
        float4 p2 = *(const float4*)(part2 + idx);
        float4 bb = *(const float4*)(bias + n);
        o.x += p.x + p2.x + bb.x; o.y += p.y + p2.y + bb.y;
        o.z += p.z + p2.z + bb.z; o.w += p.w + p2.w + bb.w;
        *(float4*)(out + idx) = o;
        return;
    }
    int ten = b - 4096;
    const unsigned int* h = hist + (long)ten * 16384;
    __shared__ unsigned int partl[256];
    unsigned int s = 0;
    for (int bb = 0; bb < 64; ++bb) s += h[t * 64 + bb];
    partl[t] = s;
    __syncthreads();
    if (t == 0) {
        long k = (ten == 5) ? TOTP / 2 : (long)S_LEN * H_DIM / 2;
        long c = 0;
        int ch = 0;
        for (; ch < 256; ++ch) {
            if (c + (long)partl[ch] >= k) break;
            c += partl[ch];
        }
        int bin = ch * 64;
        for (;; ++bin) {
            unsigned int hv = h[bin];
            if (c + (long)hv >= k) break;
            c += hv;
        }
        int slot = (ten == 4) ? 5 : (ten == 5) ? 4 : ten;
        out_kth[slot] = __builtin_bit_cast(float, (unsigned int)bin << 16);
    }
}

// ==================================================================
extern "C" void kernel_launch(void* const* d_in, const int* in_sizes, int n_in,
                              void* d_out, int out_size, void* d_ws, size_t ws_size,
                              hipStream_t stream) {
    (void)in_sizes; (void)n_in; (void)out_size; (void)ws_size;
    const float* x = (const float*)d_in[0];
    const int*   wcodes[4] = {(const int*)d_in[1], (const int*)d_in[6],
                              (const int*)d_in[11], (const int*)d_in[16]};
    const float* wabs[4]   = {(const float*)d_in[2], (const float*)d_in[7],
                              (const float*)d_in[12], (const float*)d_in[17]};
    const float* bias[4]   = {(const float*)d_in[3], (const float*)d_in[8],
                              (const float*)d_in[13], (const float*)d_in[18]};
    const float* lA[4]     = {(const float*)d_in[4], (const float*)d_in[9],
                              (const float*)d_in[14], (const float*)d_in[19]};
    const float* lB[4]     = {(const float*)d_in[5], (const float*)d_in[10],
                              (const float*)d_in[15], (const float*)d_in[20]};

    char* wp = (char*)d_ws;
    auto alloc = [&](size_t bytes) {
        char* p = wp; wp += (bytes + 255) & ~(size_t)255; return p;
    };
    const size_t SH  = (size_t)S_LEN * H_DIM;       // 4,194,304
    const long   nW  = (long)H_DIM * H_DIM;
    unsigned short* xb_ext = (unsigned short*)alloc((size_t)S_LEN * KE3 * 2);
    unsigned short* qkvb   = (unsigned short*)alloc(3 * SH * 2);  // q,k,v bf16
    unsigned short* vT     = (unsigned short*)alloc(SH * 2);
    unsigned short* ob_ext = (unsigned short*)alloc((size_t)S_LEN * KEO * 2);
    unsigned short* Wd_ext = (unsigned short*)alloc((size_t)H_DIM * KEO * 2);
    float*        opart  = (float*)alloc(SH * 4);
    float*        bias3  = (float*)alloc(3 * H_DIM * 4);
    unsigned int* hist   = (unsigned int*)alloc(6 * 16384 * 4);
    // bigbuf: first holds Wqkv_ext (102 MB). After QKV it is dead; scores16
    // (bf16 P, 67 MB) aliases its head, and opart2 (16.8 MB, split-K3 third
    // partial) aliases bytes [67.1MB, 84MB) — disjoint lifetimes verified:
    // opart2 written step 7, read step 9; scores16 read through step 8.
    char* bigbuf = alloc((size_t)3 * H_DIM * KE3 * 2);
    unsigned short* Wqkv_ext = (unsigned short*)bigbuf;
    unsigned short* scores16 = (unsigned short*)bigbuf;
    float*          opart2   = (float*)(bigbuf + (size_t)TOTP * 2);

    float* out_final = (float*)d_out;
    float* out_kth   = out_final + SH;

    unsigned short* qb = qkvb;
    unsigned short* kb = qkvb + SH;
    unsigned short* vb = qkvb + 2 * SH;

    // 0) x cast + lora_a
    xcast_lora<<<S_LEN, 256, 0, stream>>>(x, lA[0], lA[1], lA[2], xb_ext);

    // 1) prep: dequants + pads + bias + hist zero
    prep_weights<<<dim3(9600, 4), 256, 0, stream>>>(
        wcodes[0], wcodes[1], wcodes[2], wcodes[3],
        wabs[0], wabs[1], wabs[2], wabs[3],
        lB[0], lB[1], lB[2], lB[3],
        bias[0], bias[1], bias[2],
        Wqkv_ext, Wd_ext, bias3, hist, nW);

    // 2) QKV: ONE z=3 batched GEMM over K=4160 (runtime args — round-9 lesson)
    gemm_qkv<<<dim3(32, 8, 3), 256, 0, stream>>>(
        xb_ext, Wqkv_ext, qkvb, nullptr, bias3, KE3, KE3, KE3, H_DIM,
        0, (long)H_DIM * KE3, (long)SH, 1.0f, nullptr, nullptr);

    // 3) scores16 = q.kT / sqrt(128) bf16 (36 tri tiles/head) + v->vT (x>=36 region)
    gemm_scores<<<dim3(40, 1, NHEAD), 256, 0, stream>>>(
        qb, kb, scores16, nullptr, nullptr, HEAD_D, H_DIM, H_DIM, S_LEN,
        128, 128, (long)S_LEN * S_LEN, 0.08838834764831845f, vb, vT);

    // 4) softmax in-place bf16, vectorized, 2 concurrent balanced rows/block
    softmax_causal<<<NHEAD * S_LEN / 2, 256, 0, stream>>>(scores16);

    // 5) o = P.v -> ob_ext (bf16, row stride KEO); K limited to bm+128
    gemm_pv<<<dim3(1, 8, NHEAD), 256, 0, stream>>>(
        scores16, vT, ob_ext, nullptr, nullptr, S_LEN,
        S_LEN, S_LEN, KEO,
        (long)S_LEN * S_LEN, (long)HEAD_D * S_LEN, 128, 1.0f, nullptr, nullptr);

    // 6) xa_o columns
    lora_ao_kernel<<<S_LEN, 256, 0, stream>>>(ob_ext, lA[3]);

    // 7) O projection: split-K3 (z=3 -> 768 blocks = 3/CU, matching QKV occupancy)
    gemm_oproj<<<dim3(32, 8, 3), 256, 0, stream>>>(
        ob_ext, Wd_ext, out_final, opart, nullptr, KEO, KEO, KEO, H_DIM,
        0, 0, 0, 1.0f, nullptr, (unsigned short*)opart2);

    // 8) k-th selects: one 6-tensor histogram (hist zeroed in prep)
    hist6<<<1536, 256, 0, stream>>>(x, qkvb, ob_ext, scores16, hist);

    // 9) finish: combine split-K3 partials + bias, and scan the 6 histograms
    finish_kernel<<<4102, 256, 0, stream>>>(out_final, opart, opart2, bias[3],
                                            hist, out_kth);
}

// Round 14
// 710.106 us; speedup vs baseline: 1.0998x; 1.0044x over previous
//
#include <hip/hip_runtime.h>

#define S_LEN  1024
#define H_DIM  4096
#define NHEAD  32
#define HEAD_D 128
#define RANK   16
#define KE3    4160   // QKV extended K: 4096 + 3*16 + 16 pad (130 * 32)
#define KEO    4160   // O-proj extended K: 4096 + 16 + 48 pad (65 * 64) — 64-mult for BK=64
#define TOTP   ((long)NHEAD * S_LEN * S_LEN)
#define MASKED_ZEROS 16760832u   // 32 heads * 1023*1024/2 causal-masked elements

typedef __bf16 bf16x8 __attribute__((ext_vector_type(8)));
typedef float  f32x4  __attribute__((ext_vector_type(4)));
typedef unsigned short ushort8v __attribute__((ext_vector_type(8)));

#define GLOAD_LDS16(g, l) __builtin_amdgcn_global_load_lds( \
    (const __attribute__((address_space(1))) unsigned int*)(g), \
    (__attribute__((address_space(3))) unsigned int*)(l), 16, 0, 0)

__device__ const float NF4_TAB[16] = {
    -1.0f, -0.6961928009986877f, -0.5250730514526367f, -0.39491748809814453f,
    -0.28444138169288635f, -0.18477343022823334f, -0.09105003625154495f, 0.0f,
    0.07958029955625534f, 0.16093020141124725f, 0.24611230194568634f,
    0.33791524171829224f, 0.4407098591327667f, 0.5626170039176941f,
    0.7229568362236023f, 1.0f};

__device__ __forceinline__ unsigned short f2bf(float f) {
    unsigned int u = __builtin_bit_cast(unsigned int, f);
    u = (u + 0x7FFFu + ((u >> 16) & 1u)) >> 16;   // RNE
    return (unsigned short)u;
}

__device__ __forceinline__ float bf2f(unsigned short s) {
    return __builtin_bit_cast(float, (unsigned int)s << 16);
}

// ---------------- plain dequant NF4 -> bf16, strided output row ----------------
__device__ __forceinline__ void dequant_body(
    const int* __restrict__ codes, const float* __restrict__ absmax,
    unsigned short* __restrict__ out, long i, int ostride) {
    int4 c0 = *(const int4*)(codes + i);
    int4 c1 = *(const int4*)(codes + i + 4);
    float am = absmax[i >> 6];
    long orow = i >> 12;                 // H_DIM = 4096
    int  col  = (int)(i & 4095);
    ushort8v r;
    r[0] = f2bf(NF4_TAB[c0.x] * am);
    r[1] = f2bf(NF4_TAB[c0.y] * am);
    r[2] = f2bf(NF4_TAB[c0.z] * am);
    r[3] = f2bf(NF4_TAB[c0.w] * am);
    r[4] = f2bf(NF4_TAB[c1.x] * am);
    r[5] = f2bf(NF4_TAB[c1.y] * am);
    r[6] = f2bf(NF4_TAB[c1.z] * am);
    r[7] = f2bf(NF4_TAB[c1.w] * am);
    *(ushort8v*)(out + orow * ostride + col) = r;
}

// -------- x cast + 3x lora_a, one row per block ----
__global__ __launch_bounds__(256) void xcast_lora(
    const float* __restrict__ x, const float* __restrict__ la0,
    const float* __restrict__ la1, const float* __restrict__ la2,
    unsigned short* __restrict__ xb_ext) {
    __shared__ float xs[4096];
    int m = (int)blockIdx.x;
    int tid = threadIdx.x;
    const float* xr = x + (long)m * H_DIM;
    int c = tid * 16;
    float4 f0 = *(const float4*)(xr + c);
    float4 f1 = *(const float4*)(xr + c + 4);
    float4 f2 = *(const float4*)(xr + c + 8);
    float4 f3 = *(const float4*)(xr + c + 12);
    *(float4*)(xs + c)      = f0;
    *(float4*)(xs + c + 4)  = f1;
    *(float4*)(xs + c + 8)  = f2;
    *(float4*)(xs + c + 12) = f3;
    ushort8v r0, r1;
    r0[0] = f2bf(f0.x); r0[1] = f2bf(f0.y); r0[2] = f2bf(f0.z); r0[3] = f2bf(f0.w);
    r0[4] = f2bf(f1.x); r0[5] = f2bf(f1.y); r0[6] = f2bf(f1.z); r0[7] = f2bf(f1.w);
    r1[0] = f2bf(f2.x); r1[1] = f2bf(f2.y); r1[2] = f2bf(f2.z); r1[3] = f2bf(f2.w);
    r1[4] = f2bf(f3.x); r1[5] = f2bf(f3.y); r1[6] = f2bf(f3.z); r1[7] = f2bf(f3.w);
    unsigned short* orow = xb_ext + (long)m * KE3 + c;
    *(ushort8v*)orow = r0;
    *(ushort8v*)(orow + 8) = r1;
    __syncthreads();
    int w = tid >> 6, lane = tid & 63;
    if (w < 3) {
        const float* la = (w == 0) ? la0 : (w == 1) ? la1 : la2;
        float s[16];
#pragma unroll
        for (int r = 0; r < 16; ++r) s[r] = 0.f;
        for (int k = lane; k < H_DIM; k += 64) {
            float xv = xs[k];
            const float4* lr = (const float4*)(la + (long)k * RANK);
            float4 q0 = lr[0], q1 = lr[1], q2 = lr[2], q3 = lr[3];
            s[0] += xv * q0.x;  s[1] += xv * q0.y;  s[2] += xv * q0.z;  s[3] += xv * q0.w;
            s[4] += xv * q1.x;  s[5] += xv * q1.y;  s[6] += xv * q1.z;  s[7] += xv * q1.w;
            s[8] += xv * q2.x;  s[9] += xv * q2.y;  s[10] += xv * q2.z; s[11] += xv * q2.w;
            s[12] += xv * q3.x; s[13] += xv * q3.y; s[14] += xv * q3.z; s[15] += xv * q3.w;
        }
        for (int off = 32; off; off >>= 1)
#pragma unroll
            for (int r = 0; r < 16; ++r) s[r] += __shfl_xor(s[r], off);
        if (lane == 0)
#pragma unroll
            for (int r = 0; r < 16; ++r)
                xb_ext[(long)m * KE3 + 4096 + 16 * w + r] = f2bf(s[r]);
    } else if (lane < 16) {
        // zero the 16 alignment-pad columns [4144,4160)
        xb_ext[(long)m * KE3 + 4144 + lane] = 0;
    }
}

// -------- prep: 4 dequants + lbT pads + bias + hist zero (no LDS) --------
// grid dim3(9600, 4):
//  bx<8192               : dequant main region (all p), one-shot 8 elem/thread
//  p<3,  bx in [8192,9216): lbT/zero pad cols (64/row) + bias gather
//  p==3, bx in [8192,9216): wo pad cols (64/row, KEO=4160)
//  p==1, bx in [9216,9600): zero hist buffer (6*16384 uints)
// NOTE (round 8 lesson): moving the Wd dequant into the QKV GEMM as 192
// grid-stride blocks REGRESSED +65us — a fused BW-region needs the same
// TLP shape as the standalone kernel (2048 one-shot blocks).
__global__ __launch_bounds__(256) void prep_weights(
    const int* __restrict__ c0, const int* __restrict__ c1,
    const int* __restrict__ c2, const int* __restrict__ c3,
    const float* __restrict__ a0, const float* __restrict__ a1,
    const float* __restrict__ a2, const float* __restrict__ a3,
    const float* __restrict__ lb0, const float* __restrict__ lb1,
    const float* __restrict__ lb2, const float* __restrict__ lb3,
    const float* __restrict__ b0, const float* __restrict__ b1,
    const float* __restrict__ b2,
    unsigned short* __restrict__ wqkv, unsigned short* __restrict__ wo,
    float* __restrict__ bias3, unsigned int* __restrict__ hist, long n) {
    int p = blockIdx.y;
    long bx = blockIdx.x;
    int tid = threadIdx.x;
    if (bx < 8192) {
        const int* codes = (p == 0) ? c0 : (p == 1) ? c1 : (p == 2) ? c2 : c3;
        const float* am  = (p == 0) ? a0 : (p == 1) ? a1 : (p == 2) ? a2 : a3;
        long i = (bx * 256 + tid) * 8;
        if (i >= n) return;
        if (p < 3) dequant_body(codes, am, wqkv + (size_t)p * H_DIM * KE3, i, KE3);
        else       dequant_body(codes, am, wo, i, KEO);
        return;
    }
    if (bx < 9216) {
        long g = (bx - 8192) * 256 + tid;
        int row = (int)(g >> 6), c = (int)(g & 63);
        if (p < 3) {
            const float* lb = (p == 0) ? lb0 : (p == 1) ? lb1 : lb2;
            unsigned int r = (unsigned int)(c - 16 * p);
            float v = (r < 16u) ? lb[r * H_DIM + row] : 0.f;
            wqkv[(size_t)p * H_DIM * KE3 + (long)row * KE3 + 4096 + c] = f2bf(v);
            if (g < H_DIM) {
                const float* bp = (p == 0) ? b0 : (p == 1) ? b1 : b2;
                bias3[(size_t)p * H_DIM + g] = bp[g];
            }
            return;
        }
        // p == 3: wo pad cols [4096,4160)
        float v = (c < 16) ? lb3[c * H_DIM + row] : 0.f;
        wo[(long)row * KEO + 4096 + c] = f2bf(v);
        return;
    }
    if (p == 1) {
        long g = (bx - 9216) * 256 + tid;
        if (g < 6 * 16384) hist[g] = 0u;
    }
}

// xa_o = ob @ la_o (bf16 in) -> bf16 cols of ob_ext — ushort8-vectorized x loads
__global__ __launch_bounds__(256) void lora_ao_kernel(
    unsigned short* __restrict__ ob_ext, const float* __restrict__ la) {
    int m = blockIdx.x;
    const unsigned short* xr = ob_ext + (long)m * KEO;
    int tid = threadIdx.x, lane = tid & 63, wid = tid >> 6;
    float s[4] = {0.f, 0.f, 0.f, 0.f};
    for (int k0 = lane * 8; k0 < H_DIM; k0 += 512) {     // 8 iters, 16B/lane
        ushort8v xv8 = *(const ushort8v*)(xr + k0);
#pragma unroll
        for (int j = 0; j < 8; ++j) {
            float xv = bf2f(xv8[j]);
            float4 q = *(const float4*)(la + (long)(k0 + j) * RANK + wid * 4);
            s[0] += xv * q.x; s[1] += xv * q.y;
            s[2] += xv * q.z; s[3] += xv * q.w;
        }
    }
    for (int off = 32; off; off >>= 1)
        for (int r = 0; r < 4; ++r) s[r] += __shfl_down(s[r], off);
    if (lane == 0) {
        for (int r = 0; r < 4; ++r)
            ob_ext[(long)m * KEO + 4096 + wid * 4 + r] = f2bf(s[r]);
        // zero pad cols [4112,4160): 12 per wave
        for (int r = 0; r < 12; ++r)
            ob_ext[(long)m * KEO + 4112 + wid * 12 + r] = 0;
    }
}

// ---------------- bf16 NT GEMM body: C[m][n] = alpha*sum_k A[m][k]*B[n][k] (+bias[n]) --
// BK=64, 128B LDS rows, XOR slot-swizzle (slot ^= row&7) -> conflict-free ds_read_b128.
// Single-buffer 2-barrier structure (measured 848 TF, 0 conflicts — round 5/7/10).
// NOTE (round 6 lesson): explicit dbuf + 64KB LDS REGRESSED (occupancy 30->16.5%,
// FETCH +40%) — reproduces learn_hip m132. Do not re-attempt at 128² tile.
// NOTE (round 9 lesson): ALL dims/strides MUST be runtime kernel args. Baking
// K=4160 as a device-side literal unrolled the 65-iter K-loop -> VGPR 80->88,
// occupancy 31->16.5%, 127->198us.
// MODE 0: plain batched (z). MODE 1: causal triangular grid (x<36: tri idx, z=head;
//         x in [36,40): v->vT transpose region). MODE 2: batched + K limited to
//         bm+128 (causal PV). MODE 3: split-K3 (z thirds -> Cv/Cv2/tdst, f32 out).
template<int MODE>
__device__ __forceinline__ void gemm_body(
    const unsigned short* __restrict__ A, const unsigned short* __restrict__ B,
    void* __restrict__ Cv, void* __restrict__ Cv2, const float* __restrict__ bias,
    int K, int lda, int ldb, int ldc,
    long strideA, long strideB, long strideC, float alpha,
    const unsigned short* __restrict__ tsrc, unsigned short* __restrict__ tdst) {
    __shared__ unsigned short As[128][64];   // 16 KB each, 128B rows (8 swizzle slots)
    __shared__ unsigned short Bs[128][64];
    const int tid = threadIdx.x;
    int bm, bn;
    int k0s = 0, k0e = K;
    if (MODE == 1) {
        int i = blockIdx.x;
        if (i >= 36) {
            // transpose region: 128 blocks, 32x32 tiles, padded LDS overlay
            unsigned short (*tl)[33] = (unsigned short(*)[33])&As[0][0];
            int tb = (i - 36) + 4 * blockIdx.z;
            int tx = tid & 31, ty = tid >> 5;           // 8 rows per pass
            for (int tile = tb; tile < 4096; tile += 128) {
                int tc = tile & 127, ts = tile >> 7;
                int c0 = tc * 32, s0 = ts * 32;
                for (int j = 0; j < 32; j += 8)
                    tl[ty + j][tx] = tsrc[(long)(s0 + ty + j) * H_DIM + c0 + tx];
                __syncthreads();
                for (int j = 0; j < 32; j += 8)
                    tdst[(long)(c0 + ty + j) * S_LEN + s0 + tx] = tl[tx][ty + j];
                __syncthreads();
            }
            return;
        }
        int tm = (int)((sqrtf(8.f * i + 1.f) - 1.f) * 0.5f);
        if ((tm + 1) * (tm + 2) / 2 <= i) tm++;
        if (tm * (tm + 1) / 2 > i) tm--;
        int tn = i - tm * (tm + 1) / 2;
        bm = tm * 128; bn = tn * 128;
    } else {
        bm = blockIdx.y * 128; bn = blockIdx.x * 128;
        if (MODE == 2) { int kl = bm + 128; if (kl < k0e) k0e = kl; }
    }
    const unsigned short* Ab = A;
    const unsigned short* Bb = B;
    long coff = 0;
    void* Cuse = Cv;
    if (MODE == 3) {
        int Kq = (K / 3) & ~63;
        k0s = (int)blockIdx.z * Kq;
        k0e = (blockIdx.z == 2) ? K : k0s + Kq;
        Cuse = (blockIdx.z == 0) ? Cv : (blockIdx.z == 1) ? Cv2 : (void*)tdst;
    } else {
        Ab += (long)blockIdx.z * strideA;
        Bb += (long)blockIdx.z * strideB;
        coff = (long)blockIdx.z * strideC;
    }
    const int lane = tid & 63, wid = tid >> 6;
    const int wm = (wid >> 1) * 64, wn = (wid & 1) * 64;
    // staging: pass p covers LDS rows [p*32 + wid*8, +8); lane -> row l>>3, slot l&7
    const int srow = lane >> 3;
    const int scol = ((lane & 7) ^ srow) << 3;          // pre-swizzled source col
    const int r0 = wid * 8 + srow;
    const unsigned short* gA0 = Ab + (long)(bm + r0) * lda + scol;
    const unsigned short* gB0 = Bb + (long)(bn + r0) * ldb + scol;
    f32x4 acc[4][4] = {};
    const int q = lane >> 4, rr = lane & 15;
    const int colh0 = ((q ^ (rr & 7)) << 3);            // k-half 0 slots (0..3 ^ row)
    const int colh1 = colh0 ^ 32;                       // k-half 1 (bit2 of slot)
    for (int k0 = k0s; k0 < k0e; k0 += 64) {
#pragma unroll
        for (int p = 0; p < 4; ++p) {
            GLOAD_LDS16(gA0 + (long)p * 32 * lda + k0, &As[p * 32 + wid * 8][0]);
            GLOAD_LDS16(gB0 + (long)p * 32 * ldb + k0, &Bs[p * 32 + wid * 8][0]);
        }
        __syncthreads();
        bf16x8 af[4], bfr[4];
#pragma unroll
        for (int i = 0; i < 4; ++i) {
            af[i]  = __builtin_bit_cast(bf16x8, *(const uint4*)&As[wm + i * 16 + rr][colh0]);
            bfr[i] = __builtin_bit_cast(bf16x8, *(const uint4*)&Bs[wn + i * 16 + rr][colh0]);
        }
#pragma unroll
        for (int i = 0; i < 4; ++i)
#pragma unroll
            for (int j = 0; j < 4; ++j)
                acc[i][j] = __builtin_amdgcn_mfma_f32_16x16x32_bf16(
                    af[i], bfr[j], acc[i][j], 0, 0, 0);
#pragma unroll
        for (int i = 0; i < 4; ++i) {
            af[i]  = __builtin_bit_cast(bf16x8, *(const uint4*)&As[wm + i * 16 + rr][colh1]);
            bfr[i] = __builtin_bit_cast(bf16x8, *(const uint4*)&Bs[wn + i * 16 + rr][colh1]);
        }
#pragma unroll
        for (int i = 0; i < 4; ++i)
#pragma unroll
            for (int j = 0; j < 4; ++j)
                acc[i][j] = __builtin_amdgcn_mfma_f32_16x16x32_bf16(
                    af[i], bfr[j], acc[i][j], 0, 0, 0);
        __syncthreads();
    }
    const int cr = (lane >> 4) * 4;
    const int cc = lane & 15;
    float bv[4];
#pragma unroll
    for (int j = 0; j < 4; ++j)
        bv[j] = bias ? bias[(long)blockIdx.z * H_DIM + bn + wn + j * 16 + cc] : 0.f;
    if (MODE != 3) {
        unsigned short* Cb = (unsigned short*)Cuse + coff;
        for (int i = 0; i < 4; ++i)
            for (int j = 0; j < 4; ++j) {
                unsigned short* cp = Cb + (long)(bm + wm + i * 16 + cr) * ldc
                                        + (bn + wn + j * 16 + cc);
                for (int r = 0; r < 4; ++r)
                    cp[(long)r * ldc] = f2bf(acc[i][j][r] * alpha + bv[j]);
            }
    } else {
        float* Cb = (float*)Cuse + coff;
        for (int i = 0; i < 4; ++i)
            for (int j = 0; j < 4; ++j) {
                float* cp = Cb + (long)(bm + wm + i * 16 + cr) * ldc
                               + (bn + wn + j * 16 + cc);
                for (int r = 0; r < 4; ++r)
                    cp[(long)r * ldc] = acc[i][j][r] * alpha + bv[j];
            }
    }
}

// Named wrappers — distinct Kernel_Name per stage; ALL params runtime-forwarded
// (round-9 lesson: do NOT bake dims device-side).
__global__ __launch_bounds__(256) void gemm_qkv(
    const unsigned short* __restrict__ A, const unsigned short* __restrict__ B,
    void* __restrict__ Cv, void* __restrict__ Cv2, const float* __restrict__ bias,
    int K, int lda, int ldb, int ldc,
    long strideA, long strideB, long strideC, float alpha,
    const unsigned short* __restrict__ tsrc, unsigned short* __restrict__ tdst) {
    gemm_body<0>(A, B, Cv, Cv2, bias, K, lda, ldb, ldc,
                 strideA, strideB, strideC, alpha, tsrc, tdst);
}

__global__ __launch_bounds__(256) void gemm_scores(
    const unsigned short* __restrict__ A, const unsigned short* __restrict__ B,
    void* __restrict__ Cv, void* __restrict__ Cv2, const float* __restrict__ bias,
    int K, int lda, int ldb, int ldc,
    long strideA, long strideB, long strideC, float alpha,
    const unsigned short* __restrict__ tsrc, unsigned short* __restrict__ tdst) {
    gemm_body<1>(A, B, Cv, Cv2, bias, K, lda, ldb, ldc,
                 strideA, strideB, strideC, alpha, tsrc, tdst);
}

__global__ __launch_bounds__(256) void gemm_pv(
    const unsigned short* __restrict__ A, const unsigned short* __restrict__ B,
    void* __restrict__ Cv, void* __restrict__ Cv2, const float* __restrict__ bias,
    int K, int lda, int ldb, int ldc,
    long strideA, long strideB, long strideC, float alpha,
    const unsigned short* __restrict__ tsrc, unsigned short* __restrict__ tdst) {
    gemm_body<2>(A, B, Cv, Cv2, bias, K, lda, ldb, ldc,
                 strideA, strideB, strideC, alpha, tsrc, tdst);
}

__global__ __launch_bounds__(256) void gemm_oproj(
    const unsigned short* __restrict__ A, const unsigned short* __restrict__ B,
    void* __restrict__ Cv, void* __restrict__ Cv2, const float* __restrict__ bias,
    int K, int lda, int ldb, int ldc,
    long strideA, long strideB, long strideC, float alpha,
    const unsigned short* __restrict__ tsrc, unsigned short* __restrict__ tdst) {
    gemm_body<3>(A, B, Cv, Cv2, bias, K, lda, ldb, ldc,
                 strideA, strideB, strideC, alpha, tsrc, tdst);
}

// ---------------- causal softmax, bf16 in/out in-place, vectorized (G13) ----------
// Block = 2 balanced rows processed CONCURRENTLY: warps 0-1 -> row pr,
// warps 2-3 -> row S-1-pr. 128 threads/row x ushort8v chunks (16B/lane).
__global__ __launch_bounds__(256) void softmax_causal(unsigned short* __restrict__ scores16) {
    int b = blockIdx.x;
    int h = b >> 9, pr = b & 511;
    int tid = threadIdx.x, lane = tid & 63, wid = tid >> 6;
    int rsel = tid >> 7;                    // 0: row pr, 1: row S-1-pr
    int c = (tid & 127) << 3;               // chunk start col (0..1016)
    __shared__ float red[4], red2[4];
    int i = rsel ? (S_LEN - 1 - pr) : pr;
    unsigned short* row = scores16 + ((long)h * S_LEN + i) * S_LEN;
    int L = i + 1;
    ushort8v v8 = *(const ushort8v*)(row + c);
    float v[8];
    float mx = -1e30f;
#pragma unroll
    for (int j = 0; j < 8; ++j) {
        v[j] = (c + j < L) ? bf2f(v8[j]) : -1e30f;
        mx = fmaxf(mx, v[j]);
    }
    for (int off = 32; off; off >>= 1) mx = fmaxf(mx, __shfl_xor(mx, off));
    if (lane == 0) red[wid] = mx;
    __syncthreads();
    mx = rsel ? fmaxf(red[2], red[3]) : fmaxf(red[0], red[1]);
    float e[8], sum = 0.f;
#pragma unroll
    for (int j = 0; j < 8; ++j) {
        e[j] = (c + j < L) ? __expf(v[j] - mx) : 0.f;
        sum += e[j];
    }
    for (int off = 32; off; off >>= 1) sum += __shfl_xor(sum, off);
    if (lane == 0) red2[wid] = sum;
    __syncthreads();
    sum = rsel ? (red2[2] + red2[3]) : (red2[0] + red2[1]);
    float inv = 1.f / sum;
    ushort8v o8;
#pragma unroll
    for (int j = 0; j < 8; ++j) o8[j] = f2bf(e[j] * inv);
    *(ushort8v*)(row + c) = o8;
}

// ---------------- mega histogram: 6 tensors, flat weighted grid (1536 blocks) ----
// [0,256) x fp32 | [256,384) q | [384,512) k | [512,640) v | [640,768) o |
// [768,1536) P: CAUSAL TRIANGLE ONLY (round-14) — balanced row-pairs (i,1023-i),
// one pair per wave, per-element masking; the 16.76M masked zeros are added as
// one analytic constant. Halves the P read: 67.1 -> 33.6 MB.
__global__ __launch_bounds__(256, 2) void hist6(
    const float* __restrict__ x, const unsigned short* __restrict__ qkv,
    const unsigned short* __restrict__ ob, const unsigned short* __restrict__ P,
    unsigned int* __restrict__ hist) {
    __shared__ unsigned int lh[16384];
    const long SH = (long)S_LEN * H_DIM;
    int t = threadIdx.x;
    int b = blockIdx.x;
    int ten, b0, nblk;
    if (b < 256)      { ten = 0; b0 = 0;   nblk = 256; }
    else if (b < 384) { ten = 1; b0 = 256; nblk = 128; }
    else if (b < 512) { ten = 2; b0 = 384; nblk = 128; }
    else if (b < 640) { ten = 3; b0 = 512; nblk = 128; }
    else if (b < 768) { ten = 4; b0 = 640; nblk = 128; }
    else              { ten = 5; b0 = 768; nblk = 768; }
    unsigned int* gh = hist + (long)ten * 16384;
    for (int k = t; k < 16384; k += 256) lh[k] = 0u;
    __syncthreads();
    if (ten == 0) {
        long i = (long)(b - b0) * 256 + t;
        long stride = (long)nblk * 256;
        for (; i < SH / 4; i += stride) {
            float4 v = *(const float4*)(x + i * 4);
            unsigned int u0 = (__builtin_bit_cast(unsigned int, v.x) & 0x7FFFFFFFu) >> 16;
            unsigned int u1 = (__builtin_bit_cast(unsigned int, v.y) & 0x7FFFFFFFu) >> 16;
            unsigned int u2 = (__builtin_bit_cast(unsigned int, v.z) & 0x7FFFFFFFu) >> 16;
            unsigned int u3 = (__builtin_bit_cast(unsigned int, v.w) & 0x7FFFFFFFu) >> 16;
            atomicAdd(&lh[u0 < 16384u ? u0 : 16383u], 1u);
            atomicAdd(&lh[u1 < 16384u ? u1 : 16383u], 1u);
            atomicAdd(&lh[u2 < 16384u ? u2 : 16383u], 1u);
            atomicAdd(&lh[u3 < 16384u ? u3 : 16383u], 1u);
        }
    } else if (ten <= 3) {
        long i = (long)(b - b0) * 256 + t;
        long stride = (long)nblk * 256;
        const unsigned short* src = qkv + (size_t)(ten - 1) * SH;
        for (; i < SH / 8; i += stride) {
            ushort8v v = ((const ushort8v*)src)[i];
#pragma unroll
            for (int j = 0; j < 8; ++j) {
                unsigned int u = v[j] & 0x7FFFu;
                atomicAdd(&lh[u < 16384u ? u : 16383u], 1u);
            }
        }
    } else if (ten == 4) {
        long i = (long)(b - b0) * 256 + t;
        long stride = (long)nblk * 256;
        for (; i < SH / 8; i += stride) {
            long off = (i >> 9) * KEO + ((i & 511) << 3);
            ushort8v v = *(const ushort8v*)(ob + off);
#pragma unroll
            for (int j = 0; j < 8; ++j) {
                unsigned int u = v[j] & 0x7FFFu;
                atomicAdd(&lh[u < 16384u ? u : 16383u], 1u);
            }
        }
    } else {
        // P causal region: pair index pp over 32 heads x 512 pairs = 16384.
        // 4 pairs per block per sweep (one per wave); rows i (len i+1) and
        // 1023-i (len 1024-i) — combined 1025, balanced.
        unsigned int zc = 0;
        int w = t >> 6, lane = t & 63;
        for (long pp = (long)(b - 768) * 4 + w; pp < 16384; pp += 768 * 4) {
            int h = (int)(pp >> 9);
            int i = (int)(pp & 511);
            const unsigned short* rowA = P + ((long)h * S_LEN + i) * S_LEN;
            const unsigned short* rowB = P + ((long)h * S_LEN + (S_LEN - 1 - i)) * S_LEN;
            int LA = i + 1, LB = S_LEN - i;
            for (int c = lane * 8; c < LA; c += 512) {
                ushort8v v = *(const ushort8v*)(rowA + c);
#pragma unroll
                for (int j = 0; j < 8; ++j) {
                    if (c + j < LA) {
                        unsigned int u = v[j];
                        if (u == 0) zc++;
                        else atomicAdd(&lh[u < 16384u ? u : 16383u], 1u);
                    }
                }
            }
            for (int c = lane * 8; c < LB; c += 512) {
                ushort8v v = *(const ushort8v*)(rowB + c);
#pragma unroll
                for (int j = 0; j < 8; ++j) {
                    if (c + j < LB) {
                        unsigned int u = v[j];
                        if (u == 0) zc++;
                        else atomicAdd(&lh[u < 16384u ? u : 16383u], 1u);
                    }
                }
            }
        }
        if (zc) atomicAdd(&lh[0], zc);
        if (b == 768 && t == 0) atomicAdd(&gh[0], MASKED_ZEROS);
    }
    __syncthreads();
    for (int k = t; k < 16384; k += 256) {
        unsigned int c = lh[k];
        if (c) atomicAdd(&gh[k], c);
    }
}

// ---------------- finish: combine split-K3 + bias (b<4096) | scan6 (b>=4096) ------
__global__ __launch_bounds__(256) void finish_kernel(
    float* __restrict__ out, const float* __restrict__ part,
    const float* __restrict__ part2,
    const float* __restrict__ bias, const unsigned int* __restrict__ hist,
    float* __restrict__ out_kth) {
    int b = blockIdx.x;
    int t = threadIdx.x;
    if (b < 4096) {
        long idx = ((long)b * 256 + t) * 4;
        int n = (int)(idx & 4095);
        float4 o = *(float4*)(out + idx);
        float4 p = *(const float4*)(part + idx);
        float4 p2 = *(const float4*)(part2 + idx);
        float4 bb = *(const float4*)(bias + n);
        o.x += p.x + p2.x + bb.x; o.y += p.y + p2.y + bb.y;
        o.z += p.z + p2.z + bb.z; o.w += p.w + p2.w + bb.w;
        *(float4*)(out + idx) = o;
        return;
    }
    int ten = b - 4096;
    const unsigned int* h = hist + (long)ten * 16384;
    __shared__ unsigned int partl[256];
    unsigned int s = 0;
    for (int bb = 0; bb < 64; ++bb) s += h[t * 64 + bb];
    partl[t] = s;
    __syncthreads();
    if (t == 0) {
        long k = (ten == 5) ? TOTP / 2 : (long)S_LEN * H_DIM / 2;
        long c = 0;
        int ch = 0;
        for (; ch < 256; ++ch) {
            if (c + (long)partl[ch] >= k) break;
            c += partl[ch];
        }
        int bin = ch * 64;
        for (;; ++bin) {
            unsigned int hv = h[bin];
            if (c + (long)hv >= k) break;
            c += hv;
        }
        int slot = (ten == 4) ? 5 : (ten == 5) ? 4 : ten;
        out_kth[slot] = __builtin_bit_cast(float, (unsigned int)bin << 16);
    }
}

// ==================================================================
extern "C" void kernel_launch(void* const* d_in, const int* in_sizes, int n_in,
                              void* d_out, int out_size, void* d_ws, size_t ws_size,
                              hipStream_t stream) {
    (void)in_sizes; (void)n_in; (void)out_size; (void)ws_size;
    const float* x = (const float*)d_in[0];
    const int*   wcodes[4] = {(const int*)d_in[1], (const int*)d_in[6],
                              (const int*)d_in[11], (const int*)d_in[16]};
    const float* wabs[4]   = {(const float*)d_in[2], (const float*)d_in[7],
                              (const float*)d_in[12], (const float*)d_in[17]};
    const float* bias[4]   = {(const float*)d_in[3], (const float*)d_in[8],
                              (const float*)d_in[13], (const float*)d_in[18]};
    const float* lA[4]     = {(const float*)d_in[4], (const float*)d_in[9],
                              (const float*)d_in[14], (const float*)d_in[19]};
    const float* lB[4]     = {(const float*)d_in[5], (const float*)d_in[10],
                              (const float*)d_in[15], (const float*)d_in[20]};

    char* wp = (char*)d_ws;
    auto alloc = [&](size_t bytes) {
        char* p = wp; wp += (bytes + 255) & ~(size_t)255; return p;
    };
    const size_t SH  = (size_t)S_LEN * H_DIM;       // 4,194,304
    const long   nW  = (long)H_DIM * H_DIM;
    unsigned short* xb_ext = (unsigned short*)alloc((size_t)S_LEN * KE3 * 2);
    unsigned short* qkvb   = (unsigned short*)alloc(3 * SH * 2);  // q,k,v bf16
    unsigned short* vT     = (unsigned short*)alloc(SH * 2);
    unsigned short* ob_ext = (unsigned short*)alloc((size_t)S_LEN * KEO * 2);
    unsigned short* Wd_ext = (unsigned short*)alloc((size_t)H_DIM * KEO * 2);
    float*        opart  = (float*)alloc(SH * 4);
    float*        bias3  = (float*)alloc(3 * H_DIM * 4);
    unsigned int* hist   = (unsigned int*)alloc(6 * 16384 * 4);
    // bigbuf: first holds Wqkv_ext (102 MB). After QKV it is dead; scores16
    // (bf16 P, 67 MB) aliases its head, and opart2 (16.8 MB, split-K3 third
    // partial) aliases bytes [67.1MB, 84MB) — disjoint lifetimes verified:
    // opart2 written step 7, read step 9; scores16 read through step 8.
    char* bigbuf = alloc((size_t)3 * H_DIM * KE3 * 2);
    unsigned short* Wqkv_ext = (unsigned short*)bigbuf;
    unsigned short* scores16 = (unsigned short*)bigbuf;
    float*          opart2   = (float*)(bigbuf + (size_t)TOTP * 2);

    float* out_final = (float*)d_out;
    float* out_kth   = out_final + SH;

    unsigned short* qb = qkvb;
    unsigned short* kb = qkvb + SH;
    unsigned short* vb = qkvb + 2 * SH;

    // 0) x cast + lora_a
    xcast_lora<<<S_LEN, 256, 0, stream>>>(x, lA[0], lA[1], lA[2], xb_ext);

    // 1) prep: dequants + pads + bias + hist zero
    prep_weights<<<dim3(9600, 4), 256, 0, stream>>>(
        wcodes[0], wcodes[1], wcodes[2], wcodes[3],
        wabs[0], wabs[1], wabs[2], wabs[3],
        lB[0], lB[1], lB[2], lB[3],
        bias[0], bias[1], bias[2],
        Wqkv_ext, Wd_ext, bias3, hist, nW);

    // 2) QKV: ONE z=3 batched GEMM over K=4160 (runtime args — round-9 lesson)
    gemm_qkv<<<dim3(32, 8, 3), 256, 0, stream>>>(
        xb_ext, Wqkv_ext, qkvb, nullptr, bias3, KE3, KE3, KE3, H_DIM,
        0, (long)H_DIM * KE3, (long)SH, 1.0f, nullptr, nullptr);

    // 3) scores16 = q.kT / sqrt(128) bf16 (36 tri tiles/head) + v->vT (x>=36 region)
    gemm_scores<<<dim3(40, 1, NHEAD), 256, 0, stream>>>(
        qb, kb, scores16, nullptr, nullptr, HEAD_D, H_DIM, H_DIM, S_LEN,
        128, 128, (long)S_LEN * S_LEN, 0.08838834764831845f, vb, vT);

    // 4) softmax in-place bf16, vectorized, 2 concurrent balanced rows/block
    softmax_causal<<<NHEAD * S_LEN / 2, 256, 0, stream>>>(scores16);

    // 5) o = P.v -> ob_ext (bf16, row stride KEO); K limited to bm+128
    gemm_pv<<<dim3(1, 8, NHEAD), 256, 0, stream>>>(
        scores16, vT, ob_ext, nullptr, nullptr, S_LEN,
        S_LEN, S_LEN, KEO,
        (long)S_LEN * S_LEN, (long)HEAD_D * S_LEN, 128, 1.0f, nullptr, nullptr);

    // 6) xa_o columns
    lora_ao_kernel<<<S_LEN, 256, 0, stream>>>(ob_ext, lA[3]);

    // 7) O projection: split-K3 (z=3 -> 768 blocks = 3/CU, matching QKV occupancy)
    gemm_oproj<<<dim3(32, 8, 3), 256, 0, stream>>>(
        ob_ext, Wd_ext, out_final, opart, nullptr, KEO, KEO, KEO, H_DIM,
        0, 0, 0, 1.0f, nullptr, (unsigned short*)opart2);

    // 8) k-th selects: 6-tensor histogram; P pass reads causal triangle only
    hist6<<<1536, 256, 0, stream>>>(x, qkvb, ob_ext, scores16, hist);

    // 9) finish: combine split-K3 partials + bias, and scan the 6 histograms
    finish_kernel<<<4102, 256, 0, stream>>>(out_final, opart, opart2, bias[3],
                                            hist, out_kth);
}